// Round 1
// baseline (3186.440 us; speedup 1.0000x reference)
//
#include <hip/hip_runtime.h>
#include <math.h>

#define D_ 1024
#define H_ 16
#define HD_ 64
#define KW_ 4
#define I_ 2764
#define B_ 2
#define T_ 2048
#define BT_ (B_*T_)
#define ND_ (BT_*D_)      /* 4194304 */
#define NI_ (BT_*I_)      /* 11321344 */
#define NH_ (BT_*H_)      /* 65536 */
#define EPS_ 1e-6f
#define GATE_BIAS_ 4.0f

/* ---- static scratch pool (avoids any dependence on ws_size) ---- */
#define P0 0
#define P1 (ND_)
#define P2 (2*ND_)
#define P3 (3*ND_)
#define P4 (4*ND_)
#define P5 (5*ND_)            /* beta  [BT,H] */
#define P6 (5*ND_ + NH_)      /* alpha [BT,H] */
#define P7 (5*ND_ + 2*NH_)    /* g [BT,I] */
#define P8 (P7 + NI_)         /* u [BT,I] */
#define POOL_N (P8 + NI_)

__device__ float g_pool[POOL_N];

/* ---------------- RMSNorm: out = x * rsqrt(mean(x^2)+eps) * w ---------------- */
__global__ __launch_bounds__(256) void rmsnorm_k(const float* __restrict__ xext,
                                                 int xoff, const float* __restrict__ w,
                                                 int ooff) {
  const float* x = xext ? xext : (g_pool + xoff);
  int row = blockIdx.x;
  const float* xr = x + (size_t)row * D_;
  float* orow = g_pool + ooff + (size_t)row * D_;
  int tid = threadIdx.x;
  float4 v = ((const float4*)xr)[tid];
  float ss = v.x*v.x + v.y*v.y + v.z*v.z + v.w*v.w;
  #pragma unroll
  for (int o = 32; o > 0; o >>= 1) ss += __shfl_down(ss, o);
  __shared__ float sred[4];
  __shared__ float sscale;
  if ((tid & 63) == 0) sred[tid >> 6] = ss;
  __syncthreads();
  if (tid == 0) {
    float tot = sred[0] + sred[1] + sred[2] + sred[3];
    sscale = rsqrtf(tot / (float)D_ + EPS_);
  }
  __syncthreads();
  float s = sscale;
  float4 wv = ((const float4*)w)[tid];
  float4 o;
  o.x = v.x * s * wv.x; o.y = v.y * s * wv.y;
  o.z = v.z * s * wv.z; o.w = v.w * s * wv.w;
  ((float4*)orow)[tid] = o;
}

/* ---------------- causal depthwise conv (K=4) + SiLU ---------------- */
__global__ __launch_bounds__(256) void conv_k(int inoff, const float* __restrict__ cw,
                                              const float* __restrict__ cb, int outoff) {
  int idx = blockIdx.x * 256 + threadIdx.x;   /* over BT*D */
  const float* xn = g_pool + inoff;
  int d = idx & (D_ - 1);
  int bt = idx >> 10;
  int t = bt & (T_ - 1);
  float acc = cb[d];
  #pragma unroll
  for (int j = 0; j < KW_; j++) {
    int tt = t - (KW_ - 1) + j;
    if (tt >= 0) acc += xn[(size_t)idx + (size_t)(tt - t) * D_] * cw[d * KW_ + j];
  }
  g_pool[outoff + idx] = acc / (1.f + expf(-acc));
}

/* ---------------- generic f32 GEMM: C[M,N] = pool[aoff][M,K] @ B[K,N] ---------------- */
#define GBM 64
#define GBN 64
#define GBK 16
__global__ __launch_bounds__(256) void gemm64(int aoff, const float* __restrict__ Bm,
                                              int coff, int M, int N, int Kd) {
  __shared__ float As[GBK][GBM + 4];
  __shared__ float Bs[GBK][GBN + 4];
  const float* A = g_pool + aoff;
  float* C = g_pool + coff;
  int tid = threadIdx.x;
  int m0 = blockIdx.y * GBM;
  int n0 = blockIdx.x * GBN;
  int ty = tid >> 4, tx = tid & 15;
  int ar = tid >> 2, aq = tid & 3;
  int brr = tid >> 4, bc = tid & 15;
  bool nfull = (n0 + GBN <= N);
  float acc[4][4] = {};
  for (int k0 = 0; k0 < Kd; k0 += GBK) {
    bool kfull = (k0 + GBK <= Kd);
    if (kfull) {
      float4 av = *(const float4*)(A + (size_t)(m0 + ar) * Kd + k0 + aq * 4);
      As[aq*4+0][ar] = av.x; As[aq*4+1][ar] = av.y;
      As[aq*4+2][ar] = av.z; As[aq*4+3][ar] = av.w;
      if (nfull) {
        float4 bv = *(const float4*)(Bm + (size_t)(k0 + brr) * N + n0 + bc * 4);
        *(float4*)&Bs[brr][bc*4] = bv;
      } else {
        #pragma unroll
        for (int j = 0; j < 4; j++) {
          int col = n0 + bc * 4 + j;
          Bs[brr][bc*4+j] = (col < N) ? Bm[(size_t)(k0 + brr) * N + col] : 0.f;
        }
      }
    } else {
      #pragma unroll
      for (int j = 0; j < 4; j++) {
        int kk = k0 + aq * 4 + j;
        As[aq*4+j][ar] = (kk < Kd) ? A[(size_t)(m0 + ar) * Kd + kk] : 0.f;
      }
      #pragma unroll
      for (int j = 0; j < 4; j++) {
        int col = n0 + bc * 4 + j;
        int kk = k0 + brr;
        Bs[brr][bc*4+j] = (kk < Kd && col < N) ? Bm[(size_t)kk * N + col] : 0.f;
      }
    }
    __syncthreads();
    #pragma unroll
    for (int kk = 0; kk < GBK; kk++) {
      float4 a4 = *(const float4*)&As[kk][ty * 4];
      float4 b4 = *(const float4*)&Bs[kk][tx * 4];
      float a_[4] = {a4.x, a4.y, a4.z, a4.w};
      float b_[4] = {b4.x, b4.y, b4.z, b4.w};
      #pragma unroll
      for (int i = 0; i < 4; i++)
        #pragma unroll
        for (int j = 0; j < 4; j++)
          acc[i][j] += a_[i] * b_[j];
    }
    __syncthreads();
  }
  #pragma unroll
  for (int i = 0; i < 4; i++) {
    int row = m0 + ty * 4 + i;
    if (row >= M) continue;
    #pragma unroll
    for (int j = 0; j < 4; j++) {
      int col = n0 + tx * 4 + j;
      if (col < N) C[(size_t)row * N + col] = acc[i][j];
    }
  }
}

/* ---------------- per-head l2norm of q,k in place ---------------- */
__global__ __launch_bounds__(64) void l2norm_k(int qoff, int koff) {
  int g = blockIdx.x;           /* BT*H blocks */
  int lane = threadIdx.x;       /* 64 */
  int h = g & (H_ - 1);
  int bt = g >> 4;
  size_t off = (size_t)bt * D_ + h * HD_ + lane;
  float* q = g_pool + qoff;
  float* k = g_pool + koff;
  float qv = q[off];
  float s1 = qv * qv;
  #pragma unroll
  for (int o = 32; o > 0; o >>= 1) s1 += __shfl_xor(s1, o);
  q[off] = qv * rsqrtf(s1 + EPS_);
  float kv = k[off];
  float s2 = kv * kv;
  #pragma unroll
  for (int o = 32; o > 0; o >>= 1) s2 += __shfl_xor(s2, o);
  k[off] = kv * rsqrtf(s2 + EPS_);
}

/* ---------------- sigmoid(x + bias) in place ---------------- */
__global__ __launch_bounds__(256) void sigmoid_k(int off, float bias, int n) {
  int i = blockIdx.x * 256 + threadIdx.x;
  if (i < n) {
    float v = g_pool[off + i] + bias;
    g_pool[off + i] = 1.f / (1.f + expf(-v));
  }
}

/* ---------------- gated delta rule scan ----------------
 * one block per (b,h); thread t: column vi = t&63, k-group kg = t>>6 (16 k each)
 * S[i] = state[kg*16+i][vi] in registers                                    */
__global__ __launch_bounds__(256) void scan_k(int qoff, int koff, int voff,
                                              int boff, int aoff, int ooff) {
  const float* q = g_pool + qoff;
  const float* k = g_pool + koff;
  const float* v = g_pool + voff;
  const float* beta = g_pool + boff;
  const float* alpha = g_pool + aoff;
  float* o = g_pool + ooff;
  int bh = blockIdx.x;
  int b = bh >> 4, h = bh & (H_ - 1);
  int tid = threadIdx.x;
  int vi = tid & 63;
  int kg = tid >> 6;
  float S[16];
  #pragma unroll
  for (int i = 0; i < 16; i++) S[i] = 0.f;
  __shared__ float shq[64], shk[64], shv[64];
  __shared__ float red1[64][5];
  __shared__ float red2[64][5];
  size_t base = ((size_t)b * T_) * D_ + h * HD_;
  size_t bhbase = ((size_t)b * T_) * H_ + h;
  /* prefetch t=0 */
  float rq = 0.f, rk = 0.f, rv = 0.f;
  if (tid < 64) rq = q[base + tid];
  else if (tid < 128) rk = k[base + (tid - 64)];
  else if (tid < 192) rv = v[base + (tid - 128)];
  float rb = beta[bhbase], ra = alpha[bhbase];
  for (int t = 0; t < T_; ++t) {
    if (tid < 64) shq[tid] = rq;
    else if (tid < 128) shk[tid - 64] = rk;
    else if (tid < 192) shv[tid - 128] = rv;
    float be = rb, al = ra;
    __syncthreads();                     /* B1: stage visible */
    if (t + 1 < T_) {                    /* prefetch next step */
      size_t nb = base + (size_t)(t + 1) * D_;
      if (tid < 64) rq = q[nb + tid];
      else if (tid < 128) rk = k[nb + (tid - 64)];
      else if (tid < 192) rv = v[nb + (tid - 128)];
      size_t na = bhbase + (size_t)(t + 1) * H_;
      rb = beta[na]; ra = alpha[na];
    }
    float kk[16];
    *(float4*)&kk[0]  = *(const float4*)&shk[kg * 16 + 0];
    *(float4*)&kk[4]  = *(const float4*)&shk[kg * 16 + 4];
    *(float4*)&kk[8]  = *(const float4*)&shk[kg * 16 + 8];
    *(float4*)&kk[12] = *(const float4*)&shk[kg * 16 + 12];
    float p = 0.f;
    #pragma unroll
    for (int i = 0; i < 16; i++) { S[i] *= al; p += S[i] * kk[i]; }
    red1[vi][kg] = p;
    __syncthreads();                     /* B2: pred partials ready */
    float pred = red1[vi][0] + red1[vi][1] + red1[vi][2] + red1[vi][3];
    float delta = be * (shv[vi] - pred);
    float qq[16];
    *(float4*)&qq[0]  = *(const float4*)&shq[kg * 16 + 0];
    *(float4*)&qq[4]  = *(const float4*)&shq[kg * 16 + 4];
    *(float4*)&qq[8]  = *(const float4*)&shq[kg * 16 + 8];
    *(float4*)&qq[12] = *(const float4*)&shq[kg * 16 + 12];
    float op = 0.f;
    #pragma unroll
    for (int i = 0; i < 16; i++) { S[i] += kk[i] * delta; op += S[i] * qq[i]; }
    red2[vi][kg] = op;
    __syncthreads();                     /* B3: o partials ready */
    if (kg == 0) {
      float oo = red2[vi][0] + red2[vi][1] + red2[vi][2] + red2[vi][3];
      o[base + (size_t)t * D_ + vi] = oo;
    }
  }
}

/* ---------------- elementwise adds / swiglu ---------------- */
__global__ __launch_bounds__(256) void add_ext_k(const float* __restrict__ a,
                                                 int boff, int ooff, int n) {
  int i = blockIdx.x * 256 + threadIdx.x;
  if (i < n) g_pool[ooff + i] = a[i] + g_pool[boff + i];
}
__global__ __launch_bounds__(256) void add_out_k(int aoff, int boff,
                                                 float* __restrict__ o, int n) {
  int i = blockIdx.x * 256 + threadIdx.x;
  if (i < n) o[i] = g_pool[aoff + i] + g_pool[boff + i];
}
__global__ __launch_bounds__(256) void swiglu_k(int goff, int uoff, int n) {
  int i = blockIdx.x * 256 + threadIdx.x;
  if (i < n) {
    float x = g_pool[goff + i];
    float s = x / (1.f + expf(-x));
    g_pool[goff + i] = s * g_pool[uoff + i];
  }
}

extern "C" void kernel_launch(void* const* d_in, const int* in_sizes, int n_in,
                              void* d_out, int out_size, void* d_ws, size_t ws_size,
                              hipStream_t stream) {
  const float* x   = (const float*)d_in[0];
  const float* n1w = (const float*)d_in[1];
  const float* n2w = (const float*)d_in[2];
  const float* cw  = (const float*)d_in[3];
  const float* cb  = (const float*)d_in[4];
  const float* wq  = (const float*)d_in[5];
  const float* wk  = (const float*)d_in[6];
  const float* wv  = (const float*)d_in[7];
  const float* wb  = (const float*)d_in[8];
  const float* wa  = (const float*)d_in[9];
  const float* wo  = (const float*)d_in[10];
  const float* wg  = (const float*)d_in[11];
  const float* wu  = (const float*)d_in[12];
  const float* wd  = (const float*)d_in[13];
  float* out = (float*)d_out;

  /* 1. xn = rmsnorm(x, n1w) -> P0 */
  rmsnorm_k<<<BT_, 256, 0, stream>>>(x, 0, n1w, P0);
  /* 2. xc = silu(causal_dwconv(xn)) -> P1 */
  conv_k<<<ND_ / 256, 256, 0, stream>>>(P0, cw, cb, P1);
  /* 3. projections */
  gemm64<<<dim3(16, 64), 256, 0, stream>>>(P1, wq, P2, BT_, D_, D_);
  gemm64<<<dim3(16, 64), 256, 0, stream>>>(P1, wk, P3, BT_, D_, D_);
  gemm64<<<dim3(16, 64), 256, 0, stream>>>(P1, wv, P4, BT_, D_, D_);
  gemm64<<<dim3(1, 64), 256, 0, stream>>>(P1, wb, P5, BT_, H_, D_);
  gemm64<<<dim3(1, 64), 256, 0, stream>>>(P1, wa, P6, BT_, H_, D_);
  /* 4. l2norm q,k; sigmoid gates */
  l2norm_k<<<NH_, 64, 0, stream>>>(P2, P3);
  sigmoid_k<<<NH_ / 256, 256, 0, stream>>>(P5, 0.f, NH_);
  sigmoid_k<<<NH_ / 256, 256, 0, stream>>>(P6, GATE_BIAS_, NH_);
  /* 5. gated delta rule scan -> o in P1 (xc dead) */
  scan_k<<<B_ * H_, 256, 0, stream>>>(P2, P3, P4, P5, P6, P1);
  /* 6. mix = o @ wo -> P0 (xn dead) */
  gemm64<<<dim3(16, 64), 256, 0, stream>>>(P1, wo, P0, BT_, D_, D_);
  /* 7. h = x + mix -> P0 */
  add_ext_k<<<ND_ / 256, 256, 0, stream>>>(x, P0, P0, ND_);
  /* 8. hn = rmsnorm(h, n2w) -> P2 (q dead) */
  rmsnorm_k<<<BT_, 256, 0, stream>>>(nullptr, P0, n2w, P2);
  /* 9. g = hn@wg -> P7 ; u = hn@wu -> P8 */
  gemm64<<<dim3(44, 64), 256, 0, stream>>>(P2, wg, P7, BT_, I_, D_);
  gemm64<<<dim3(44, 64), 256, 0, stream>>>(P2, wu, P8, BT_, I_, D_);
  /* 10. f = silu(g)*u -> P7 */
  swiglu_k<<<(NI_ + 255) / 256, 256, 0, stream>>>(P7, P8, NI_);
  /* 11. ffn = f @ wd -> P3 (k dead) */
  gemm64<<<dim3(16, 64), 256, 0, stream>>>(P7, wd, P3, BT_, D_, I_);
  /* 12. out = h + ffn */
  add_out_k<<<ND_ / 256, 256, 0, stream>>>(P0, P3, out, ND_);
}

// Round 2
// 2427.446 us; speedup vs baseline: 1.3127x; 1.3127x over previous
//
#include <hip/hip_runtime.h>
#include <math.h>

#define D_ 1024
#define H_ 16
#define HD_ 64
#define KW_ 4
#define I_ 2764
#define B_ 2
#define T_ 2048
#define BT_ (B_*T_)
#define ND_ (BT_*D_)      /* 4194304 */
#define NI_ (BT_*I_)      /* 11321344 */
#define NH_ (BT_*H_)      /* 65536 */
#define EPS_ 1e-6f
#define GATE_BIAS_ 4.0f

/* ---- static scratch pool (avoids any dependence on ws_size) ---- */
#define P0 0
#define P1 (ND_)
#define P2 (2*ND_)
#define P3 (3*ND_)
#define P4 (4*ND_)
#define P5 (5*ND_)            /* beta  [BT,H] */
#define P6 (5*ND_ + NH_)      /* alpha [BT,H] */
#define P7 (5*ND_ + 2*NH_)    /* g [BT,I] */
#define P8 (P7 + NI_)         /* u [BT,I] */
#define POOL_N (P8 + NI_)

__device__ float g_pool[POOL_N];

/* ---------------- RMSNorm: out = x * rsqrt(mean(x^2)+eps) * w ---------------- */
__global__ __launch_bounds__(256) void rmsnorm_k(const float* __restrict__ xext,
                                                 int xoff, const float* __restrict__ w,
                                                 int ooff) {
  const float* x = xext ? xext : (g_pool + xoff);
  int row = blockIdx.x;
  const float* xr = x + (size_t)row * D_;
  float* orow = g_pool + ooff + (size_t)row * D_;
  int tid = threadIdx.x;
  float4 v = ((const float4*)xr)[tid];
  float ss = v.x*v.x + v.y*v.y + v.z*v.z + v.w*v.w;
  #pragma unroll
  for (int o = 32; o > 0; o >>= 1) ss += __shfl_down(ss, o);
  __shared__ float sred[4];
  __shared__ float sscale;
  if ((tid & 63) == 0) sred[tid >> 6] = ss;
  __syncthreads();
  if (tid == 0) {
    float tot = sred[0] + sred[1] + sred[2] + sred[3];
    sscale = rsqrtf(tot / (float)D_ + EPS_);
  }
  __syncthreads();
  float s = sscale;
  float4 wv = ((const float4*)w)[tid];
  float4 o;
  o.x = v.x * s * wv.x; o.y = v.y * s * wv.y;
  o.z = v.z * s * wv.z; o.w = v.w * s * wv.w;
  ((float4*)orow)[tid] = o;
}

/* ---------------- causal depthwise conv (K=4) + SiLU ---------------- */
__global__ __launch_bounds__(256) void conv_k(int inoff, const float* __restrict__ cw,
                                              const float* __restrict__ cb, int outoff) {
  int idx = blockIdx.x * 256 + threadIdx.x;   /* over BT*D */
  const float* xn = g_pool + inoff;
  int d = idx & (D_ - 1);
  int bt = idx >> 10;
  int t = bt & (T_ - 1);
  float acc = cb[d];
  #pragma unroll
  for (int j = 0; j < KW_; j++) {
    int tt = t - (KW_ - 1) + j;
    if (tt >= 0) acc += xn[(size_t)idx + (size_t)(tt - t) * D_] * cw[d * KW_ + j];
  }
  g_pool[outoff + idx] = acc / (1.f + expf(-acc));
}

/* ---------------- generic f32 GEMM: C[M,N] = pool[aoff][M,K] @ B[K,N] ---------------- */
#define GBM 64
#define GBN 64
#define GBK 16
__global__ __launch_bounds__(256) void gemm64(int aoff, const float* __restrict__ Bm,
                                              int coff, int M, int N, int Kd) {
  __shared__ float As[GBK][GBM + 4];
  __shared__ float Bs[GBK][GBN + 4];
  const float* A = g_pool + aoff;
  float* C = g_pool + coff;
  int tid = threadIdx.x;
  int m0 = blockIdx.y * GBM;
  int n0 = blockIdx.x * GBN;
  int ty = tid >> 4, tx = tid & 15;
  int ar = tid >> 2, aq = tid & 3;
  int brr = tid >> 4, bc = tid & 15;
  bool nfull = (n0 + GBN <= N);
  float acc[4][4] = {};
  for (int k0 = 0; k0 < Kd; k0 += GBK) {
    bool kfull = (k0 + GBK <= Kd);
    if (kfull) {
      float4 av = *(const float4*)(A + (size_t)(m0 + ar) * Kd + k0 + aq * 4);
      As[aq*4+0][ar] = av.x; As[aq*4+1][ar] = av.y;
      As[aq*4+2][ar] = av.z; As[aq*4+3][ar] = av.w;
      if (nfull) {
        float4 bv = *(const float4*)(Bm + (size_t)(k0 + brr) * N + n0 + bc * 4);
        *(float4*)&Bs[brr][bc*4] = bv;
      } else {
        #pragma unroll
        for (int j = 0; j < 4; j++) {
          int col = n0 + bc * 4 + j;
          Bs[brr][bc*4+j] = (col < N) ? Bm[(size_t)(k0 + brr) * N + col] : 0.f;
        }
      }
    } else {
      #pragma unroll
      for (int j = 0; j < 4; j++) {
        int kk = k0 + aq * 4 + j;
        As[aq*4+j][ar] = (kk < Kd) ? A[(size_t)(m0 + ar) * Kd + kk] : 0.f;
      }
      #pragma unroll
      for (int j = 0; j < 4; j++) {
        int col = n0 + bc * 4 + j;
        int kk = k0 + brr;
        Bs[brr][bc*4+j] = (kk < Kd && col < N) ? Bm[(size_t)kk * N + col] : 0.f;
      }
    }
    __syncthreads();
    #pragma unroll
    for (int kk = 0; kk < GBK; kk++) {
      float4 a4 = *(const float4*)&As[kk][ty * 4];
      float4 b4 = *(const float4*)&Bs[kk][tx * 4];
      float a_[4] = {a4.x, a4.y, a4.z, a4.w};
      float b_[4] = {b4.x, b4.y, b4.z, b4.w};
      #pragma unroll
      for (int i = 0; i < 4; i++)
        #pragma unroll
        for (int j = 0; j < 4; j++)
          acc[i][j] += a_[i] * b_[j];
    }
    __syncthreads();
  }
  #pragma unroll
  for (int i = 0; i < 4; i++) {
    int row = m0 + ty * 4 + i;
    if (row >= M) continue;
    #pragma unroll
    for (int j = 0; j < 4; j++) {
      int col = n0 + tx * 4 + j;
      if (col < N) C[(size_t)row * N + col] = acc[i][j];
    }
  }
}

/* ---------------- per-head l2norm of q,k in place ---------------- */
__global__ __launch_bounds__(64) void l2norm_k(int qoff, int koff) {
  int g = blockIdx.x;           /* BT*H blocks */
  int lane = threadIdx.x;       /* 64 */
  int h = g & (H_ - 1);
  int bt = g >> 4;
  size_t off = (size_t)bt * D_ + h * HD_ + lane;
  float* q = g_pool + qoff;
  float* k = g_pool + koff;
  float qv = q[off];
  float s1 = qv * qv;
  #pragma unroll
  for (int o = 32; o > 0; o >>= 1) s1 += __shfl_xor(s1, o);
  q[off] = qv * rsqrtf(s1 + EPS_);
  float kv = k[off];
  float s2 = kv * kv;
  #pragma unroll
  for (int o = 32; o > 0; o >>= 1) s2 += __shfl_xor(s2, o);
  k[off] = kv * rsqrtf(s2 + EPS_);
}

/* ---------------- sigmoid(x + bias) in place ---------------- */
__global__ __launch_bounds__(256) void sigmoid_k(int off, float bias, int n) {
  int i = blockIdx.x * 256 + threadIdx.x;
  if (i < n) {
    float v = g_pool[off + i] + bias;
    g_pool[off + i] = 1.f / (1.f + expf(-v));
  }
}

/* ---------------- gated delta rule scan, v2 ----------------
 * 2048 independent column chains: one column per 32-lane half-wave.
 * lane = 32*half + kk ; kk owns k-entries {2kk, 2kk+1} of its column.
 * Per step: 3 lane-local dots + 5-level shfl_xor reduce (stays in half),
 * no __syncthreads, no LDS. o = al*(S_prev^T q) + (k^T q)*delta.        */
#define CH 8
__device__ __forceinline__ void load_chunk(const float* kp, const float* qp,
    const float* vp, const float* bp, const float* ap, int t0, int kk,
    float2 (&kX)[CH], float2 (&qX)[CH], float (&vX)[CH], float (&bX)[CH],
    float (&aX)[CH]) {
  #pragma unroll
  for (int j = 0; j < CH; j++) {
    size_t tt = (size_t)(t0 + j);
    kX[j] = *(const float2*)(kp + tt * D_ + 2 * kk);
    qX[j] = *(const float2*)(qp + tt * D_ + 2 * kk);
    vX[j] = vp[tt * D_];
    bX[j] = bp[tt * H_];
    aX[j] = ap[tt * H_];
  }
}

__device__ __forceinline__ void steps_chunk(float2 (&kX)[CH], float2 (&qX)[CH],
    float (&vX)[CH], float (&bX)[CH], float (&aX)[CH], float& S0, float& S1,
    float* op, int t0, int kk) {
  #pragma unroll
  for (int j = 0; j < CH; j++) {
    float k0 = kX[j].x, k1 = kX[j].y, q0 = qX[j].x, q1 = qX[j].y;
    float al = aX[j], be = bX[j];
    float pk = S0 * k0 + S1 * k1;   /* partial S_prev^T k */
    float pq = S0 * q0 + S1 * q1;   /* partial S_prev^T q */
    float kq = k0 * q0 + k1 * q1;   /* partial k^T q      */
    #pragma unroll
    for (int m = 1; m < 32; m <<= 1) {
      pk += __shfl_xor(pk, m);
      pq += __shfl_xor(pq, m);
      kq += __shfl_xor(kq, m);
    }
    float pred  = al * pk;
    float delta = be * (vX[j] - pred);
    float oo    = al * pq + kq * delta;
    S0 = al * S0 + k0 * delta;
    S1 = al * S1 + k1 * delta;
    if (kk == 0) op[(size_t)(t0 + j) * D_] = oo;
  }
}

__global__ __launch_bounds__(256) void scan2_k(int qoff, int koff, int voff,
                                               int boff, int aoff, int ooff) {
  int tid = threadIdx.x;
  int gw = blockIdx.x * 4 + (tid >> 6);   /* 0..1023 */
  int lane = tid & 63;
  int vg = gw & 31;          /* column pair index */
  int bh = gw >> 5;
  int b = bh >> 4, h = bh & (H_ - 1);
  int kk = lane & 31;
  int c = vg * 2 + (lane >> 5);
  size_t kqbase = ((size_t)b * T_) * D_ + (size_t)h * HD_;
  const float* kp = g_pool + koff + kqbase;
  const float* qp = g_pool + qoff + kqbase;
  const float* vp = g_pool + voff + kqbase + c;
  const float* bp = g_pool + boff + ((size_t)b * T_) * H_ + h;
  const float* ap = g_pool + aoff + ((size_t)b * T_) * H_ + h;
  float* op = g_pool + ooff + kqbase + c;

  float S0 = 0.f, S1 = 0.f;
  float2 kA[CH], qA[CH], kB[CH], qB[CH];
  float vA[CH], bA[CH], aA[CH], vB[CH], bB[CH], aB[CH];
  load_chunk(kp, qp, vp, bp, ap, 0, kk, kA, qA, vA, bA, aA);
  for (int t0 = 0; t0 < T_; t0 += 2 * CH) {
    load_chunk(kp, qp, vp, bp, ap, t0 + CH, kk, kB, qB, vB, bB, aB);
    steps_chunk(kA, qA, vA, bA, aA, S0, S1, op, t0, kk);
    if (t0 + 2 * CH < T_)
      load_chunk(kp, qp, vp, bp, ap, t0 + 2 * CH, kk, kA, qA, vA, bA, aA);
    steps_chunk(kB, qB, vB, bB, aB, S0, S1, op, t0 + CH, kk);
  }
}

/* ---------------- elementwise adds / swiglu ---------------- */
__global__ __launch_bounds__(256) void add_ext_k(const float* __restrict__ a,
                                                 int boff, int ooff, int n) {
  int i = blockIdx.x * 256 + threadIdx.x;
  if (i < n) g_pool[ooff + i] = a[i] + g_pool[boff + i];
}
__global__ __launch_bounds__(256) void add_out_k(int aoff, int boff,
                                                 float* __restrict__ o, int n) {
  int i = blockIdx.x * 256 + threadIdx.x;
  if (i < n) o[i] = g_pool[aoff + i] + g_pool[boff + i];
}
__global__ __launch_bounds__(256) void swiglu_k(int goff, int uoff, int n) {
  int i = blockIdx.x * 256 + threadIdx.x;
  if (i < n) {
    float x = g_pool[goff + i];
    float s = x / (1.f + expf(-x));
    g_pool[goff + i] = s * g_pool[uoff + i];
  }
}

extern "C" void kernel_launch(void* const* d_in, const int* in_sizes, int n_in,
                              void* d_out, int out_size, void* d_ws, size_t ws_size,
                              hipStream_t stream) {
  const float* x   = (const float*)d_in[0];
  const float* n1w = (const float*)d_in[1];
  const float* n2w = (const float*)d_in[2];
  const float* cw  = (const float*)d_in[3];
  const float* cb  = (const float*)d_in[4];
  const float* wq  = (const float*)d_in[5];
  const float* wk  = (const float*)d_in[6];
  const float* wv  = (const float*)d_in[7];
  const float* wb  = (const float*)d_in[8];
  const float* wa  = (const float*)d_in[9];
  const float* wo  = (const float*)d_in[10];
  const float* wg  = (const float*)d_in[11];
  const float* wu  = (const float*)d_in[12];
  const float* wd  = (const float*)d_in[13];
  float* out = (float*)d_out;

  /* 1. xn = rmsnorm(x, n1w) -> P0 */
  rmsnorm_k<<<BT_, 256, 0, stream>>>(x, 0, n1w, P0);
  /* 2. xc = silu(causal_dwconv(xn)) -> P1 */
  conv_k<<<ND_ / 256, 256, 0, stream>>>(P0, cw, cb, P1);
  /* 3. projections */
  gemm64<<<dim3(16, 64), 256, 0, stream>>>(P1, wq, P2, BT_, D_, D_);
  gemm64<<<dim3(16, 64), 256, 0, stream>>>(P1, wk, P3, BT_, D_, D_);
  gemm64<<<dim3(16, 64), 256, 0, stream>>>(P1, wv, P4, BT_, D_, D_);
  gemm64<<<dim3(1, 64), 256, 0, stream>>>(P1, wb, P5, BT_, H_, D_);
  gemm64<<<dim3(1, 64), 256, 0, stream>>>(P1, wa, P6, BT_, H_, D_);
  /* 4. l2norm q,k; sigmoid gates */
  l2norm_k<<<NH_, 64, 0, stream>>>(P2, P3);
  sigmoid_k<<<NH_ / 256, 256, 0, stream>>>(P5, 0.f, NH_);
  sigmoid_k<<<NH_ / 256, 256, 0, stream>>>(P6, GATE_BIAS_, NH_);
  /* 5. gated delta rule scan -> o in P1 (xc dead) */
  scan2_k<<<256, 256, 0, stream>>>(P2, P3, P4, P5, P6, P1);
  /* 6. mix = o @ wo -> P0 (xn dead) */
  gemm64<<<dim3(16, 64), 256, 0, stream>>>(P1, wo, P0, BT_, D_, D_);
  /* 7. h = x + mix -> P0 */
  add_ext_k<<<ND_ / 256, 256, 0, stream>>>(x, P0, P0, ND_);
  /* 8. hn = rmsnorm(h, n2w) -> P2 (q dead) */
  rmsnorm_k<<<BT_, 256, 0, stream>>>(nullptr, P0, n2w, P2);
  /* 9. g = hn@wg -> P7 ; u = hn@wu -> P8 */
  gemm64<<<dim3(44, 64), 256, 0, stream>>>(P2, wg, P7, BT_, I_, D_);
  gemm64<<<dim3(44, 64), 256, 0, stream>>>(P2, wu, P8, BT_, I_, D_);
  /* 10. f = silu(g)*u -> P7 */
  swiglu_k<<<(NI_ + 255) / 256, 256, 0, stream>>>(P7, P8, NI_);
  /* 11. ffn = f @ wd -> P3 (k dead) */
  gemm64<<<dim3(16, 64), 256, 0, stream>>>(P7, wd, P3, BT_, D_, I_);
  /* 12. out = h + ffn */
  add_out_k<<<ND_ / 256, 256, 0, stream>>>(P0, P3, out, ND_);
}

// Round 3
// 1289.314 us; speedup vs baseline: 2.4714x; 1.8827x over previous
//
#include <hip/hip_runtime.h>
#include <math.h>

#define D_ 1024
#define H_ 16
#define HD_ 64
#define KW_ 4
#define I_ 2764
#define IP_ 2816              /* I padded to 22*128 */
#define B_ 2
#define T_ 2048
#define BT_ (B_*T_)           /* 4096 */
#define ND_ (BT_*D_)          /* 4194304 */
#define NIP_ (BT_*IP_)        /* 11534336 */
#define NH_ (BT_*H_)          /* 65536 */
#define EPS_ 1e-6f
#define GATE_BIAS_ 4.0f

typedef __attribute__((ext_vector_type(8))) short bf16x8;
typedef __attribute__((ext_vector_type(4))) float f32x4;

/* ---------------- static buffers ---------------- */
__device__ float f_xn[ND_];
__device__ float f_xc[ND_];
__device__ float f_q[ND_];
__device__ float f_k[ND_];
__device__ float f_v[ND_];
__device__ float f_be[NH_];
__device__ float f_al[NH_];
__device__ float f_mix[ND_];
__device__ float f_h[ND_];
__device__ float f_g[NIP_];
__device__ float f_u[NIP_];
__device__ float f_ffn[ND_];
__device__ unsigned short b_xc[ND_];
__device__ unsigned short b_o[ND_];
__device__ unsigned short b_hn[ND_];
__device__ unsigned short b_f[NIP_];
__device__ unsigned short b_wqT[D_*D_];
__device__ unsigned short b_wkT[D_*D_];
__device__ unsigned short b_wvT[D_*D_];
__device__ unsigned short b_woT[D_*D_];
__device__ unsigned short b_wgT[IP_*D_];
__device__ unsigned short b_wuT[IP_*D_];
__device__ unsigned short b_wdT[(size_t)D_*IP_];

__device__ __forceinline__ unsigned short f2b(float x) {
  union { float f; unsigned u; } a; a.f = x;
  unsigned r = a.u + 0x7fff + ((a.u >> 16) & 1);
  return (unsigned short)(r >> 16);
}

__device__ __forceinline__ const unsigned short* bsel(int id) {
  switch (id) {
    case 0: return b_xc;  case 1: return b_o;   case 2: return b_hn;
    case 3: return b_f;   case 4: return b_wqT; case 5: return b_wkT;
    case 6: return b_wvT; case 7: return b_woT; case 8: return b_wgT;
    case 9: return b_wuT; default: return b_wdT;
  }
}
__device__ __forceinline__ unsigned short* bselw(int id) {
  return (unsigned short*)bsel(id);
}
__device__ __forceinline__ float* fsel(int id) {
  switch (id) {
    case 0: return f_q;  case 1: return f_k;   case 2: return f_v;
    case 3: return f_be; case 4: return f_al;  case 5: return f_mix;
    case 6: return f_g;  case 7: return f_u;   default: return f_ffn;
  }
}

/* ---------------- RMSNorm 1: f_xn = rms(x)*w ---------------- */
__global__ __launch_bounds__(256) void rms1_k(const float* __restrict__ x,
                                              const float* __restrict__ w) {
  int row = blockIdx.x;
  const float* xr = x + (size_t)row * D_;
  int tid = threadIdx.x;
  float4 v = ((const float4*)xr)[tid];
  float ss = v.x*v.x + v.y*v.y + v.z*v.z + v.w*v.w;
  #pragma unroll
  for (int o = 32; o > 0; o >>= 1) ss += __shfl_down(ss, o);
  __shared__ float sred[4];
  __shared__ float sscale;
  if ((tid & 63) == 0) sred[tid >> 6] = ss;
  __syncthreads();
  if (tid == 0)
    sscale = rsqrtf((sred[0]+sred[1]+sred[2]+sred[3]) / (float)D_ + EPS_);
  __syncthreads();
  float s = sscale;
  float4 wv = ((const float4*)w)[tid];
  float4 o;
  o.x = v.x*s*wv.x; o.y = v.y*s*wv.y; o.z = v.z*s*wv.z; o.w = v.w*s*wv.w;
  ((float4*)(f_xn + (size_t)row * D_))[tid] = o;
}

/* ---------------- RMSNorm 2: b_hn = bf16(rms(f_h)*w) ---------------- */
__global__ __launch_bounds__(256) void rms2_k(const float* __restrict__ w) {
  int row = blockIdx.x;
  const float* xr = f_h + (size_t)row * D_;
  int tid = threadIdx.x;
  float4 v = ((const float4*)xr)[tid];
  float ss = v.x*v.x + v.y*v.y + v.z*v.z + v.w*v.w;
  #pragma unroll
  for (int o = 32; o > 0; o >>= 1) ss += __shfl_down(ss, o);
  __shared__ float sred[4];
  __shared__ float sscale;
  if ((tid & 63) == 0) sred[tid >> 6] = ss;
  __syncthreads();
  if (tid == 0)
    sscale = rsqrtf((sred[0]+sred[1]+sred[2]+sred[3]) / (float)D_ + EPS_);
  __syncthreads();
  float s = sscale;
  float4 wv = ((const float4*)w)[tid];
  unsigned short* orow = b_hn + (size_t)row * D_ + tid * 4;
  orow[0] = f2b(v.x*s*wv.x); orow[1] = f2b(v.y*s*wv.y);
  orow[2] = f2b(v.z*s*wv.z); orow[3] = f2b(v.w*s*wv.w);
}

/* ---------------- causal depthwise conv + SiLU -> f_xc, b_xc ---------------- */
__global__ __launch_bounds__(256) void conv2_k(const float* __restrict__ cw,
                                               const float* __restrict__ cb) {
  int idx = blockIdx.x * 256 + threadIdx.x;
  int d = idx & (D_ - 1);
  int bt = idx >> 10;
  int t = bt & (T_ - 1);
  float acc = cb[d];
  #pragma unroll
  for (int j = 0; j < KW_; j++) {
    int tt = t - (KW_ - 1) + j;
    if (tt >= 0) acc += f_xn[(size_t)idx + (size_t)(j - (KW_-1)) * D_] * cw[d * KW_ + j];
  }
  float s = acc / (1.f + expf(-acc));
  f_xc[idx] = s;
  b_xc[idx] = f2b(s);
}

/* ---------------- weight cast + transpose: W[K][N] f32 -> out[Np][Kp] bf16 ---------------- */
__global__ __launch_bounds__(256) void castT_k(const float* __restrict__ W,
                                               int K, int N, int outid,
                                               int Kp, int Np) {
  __shared__ float s[64][65];
  unsigned short* out = bselw(outid);
  int k0 = blockIdx.y * 64, n0 = blockIdx.x * 64;
  int tx = threadIdx.x & 63, ty = threadIdx.x >> 6;
  #pragma unroll
  for (int j = ty; j < 64; j += 4) {
    int kk = k0 + j, nn = n0 + tx;
    s[j][tx] = (kk < K && nn < N) ? W[(size_t)kk * N + nn] : 0.f;
  }
  __syncthreads();
  #pragma unroll
  for (int j = ty; j < 64; j += 4) {
    int nn = n0 + j, kk = k0 + tx;
    out[(size_t)nn * Kp + kk] = f2b(s[tx][j]);
  }
}

/* ---------------- bf16 MFMA GEMM: C[M=4096,*] = A[M,Kp] @ Bt[N,Kp]^T ----------------
 * 128x128 tile, BK=32, 4 waves (2x2), per-wave 64x64 = 4x4 x (16x16x32 MFMA).
 * global_load_lds width 16.  A, Bt bf16 row-major; C f32 row-major (ldc).   */
__global__ __launch_bounds__(256) void gemm_bf16(int aid, int bid, int cid,
                                                 int Kp, int ldc) {
  __shared__ __align__(16) unsigned short Al[128 * 32];
  __shared__ __align__(16) unsigned short Bl[128 * 32];
  const unsigned short* A = bsel(aid);
  const unsigned short* Bt = bsel(bid);
  float* C = fsel(cid);
  int tid = threadIdx.x;
  int m0 = blockIdx.y * 128, n0 = blockIdx.x * 128;
  int wave = tid >> 6, lane = tid & 63;
  int wm = (wave >> 1) * 64, wn = (wave & 1) * 64;
  int lrow = tid >> 2;            /* 0..63 staging row */
  int lcol = (tid & 3) * 8;       /* staging col (bf16) */
  f32x4 acc[4][4] = {};
  const int l15 = lane & 15, lg = lane >> 4;
  for (int k0 = 0; k0 < Kp; k0 += 32) {
    const unsigned short* Ag = A + (size_t)m0 * Kp + k0;
    const unsigned short* Bg = Bt + (size_t)n0 * Kp + k0;
    __builtin_amdgcn_global_load_lds(
      (const __attribute__((address_space(1))) void*)(Ag + (size_t)lrow * Kp + lcol),
      (__attribute__((address_space(3))) void*)(Al + wave * 512), 16, 0, 0);
    __builtin_amdgcn_global_load_lds(
      (const __attribute__((address_space(1))) void*)(Ag + (size_t)(64 + lrow) * Kp + lcol),
      (__attribute__((address_space(3))) void*)(Al + 2048 + wave * 512), 16, 0, 0);
    __builtin_amdgcn_global_load_lds(
      (const __attribute__((address_space(1))) void*)(Bg + (size_t)lrow * Kp + lcol),
      (__attribute__((address_space(3))) void*)(Bl + wave * 512), 16, 0, 0);
    __builtin_amdgcn_global_load_lds(
      (const __attribute__((address_space(1))) void*)(Bg + (size_t)(64 + lrow) * Kp + lcol),
      (__attribute__((address_space(3))) void*)(Bl + 2048 + wave * 512), 16, 0, 0);
    __syncthreads();
    bf16x8 af[4], bf[4];
    #pragma unroll
    for (int i = 0; i < 4; i++)
      af[i] = *(const bf16x8*)&Al[(wm + i * 16 + l15) * 32 + lg * 8];
    #pragma unroll
    for (int j = 0; j < 4; j++)
      bf[j] = *(const bf16x8*)&Bl[(wn + j * 16 + l15) * 32 + lg * 8];
    #pragma unroll
    for (int i = 0; i < 4; i++)
      #pragma unroll
      for (int j = 0; j < 4; j++)
        acc[i][j] = __builtin_amdgcn_mfma_f32_16x16x32_bf16(af[i], bf[j], acc[i][j], 0, 0, 0);
    __syncthreads();
  }
  #pragma unroll
  for (int i = 0; i < 4; i++) {
    int r0 = m0 + wm + i * 16 + lg * 4;
    #pragma unroll
    for (int j = 0; j < 4; j++) {
      int cc = n0 + wn + j * 16 + l15;
      #pragma unroll
      for (int r = 0; r < 4; r++)
        C[(size_t)(r0 + r) * ldc + cc] = acc[i][j][r];
    }
  }
}

/* ---------------- small f32 GEMM for beta/alpha: C[4096,16] = f_xc @ Bm[1024,16] ---------------- */
#define GBM 64
#define GBN 64
#define GBK 16
__global__ __launch_bounds__(256) void gemmba_k(const float* __restrict__ Bm, int cid) {
  __shared__ float As[GBK][GBM + 4];
  __shared__ float Bs[GBK][GBN + 4];
  const int N = H_, Kd = D_;
  float* C = fsel(cid);
  int tid = threadIdx.x;
  int m0 = blockIdx.y * GBM;
  int ty = tid >> 4, tx = tid & 15;
  int ar = tid >> 2, aq = tid & 3;
  int brr = tid >> 4, bc = tid & 15;
  float acc[4][4] = {};
  for (int k0 = 0; k0 < Kd; k0 += GBK) {
    float4 av = *(const float4*)(f_xc + (size_t)(m0 + ar) * Kd + k0 + aq * 4);
    As[aq*4+0][ar] = av.x; As[aq*4+1][ar] = av.y;
    As[aq*4+2][ar] = av.z; As[aq*4+3][ar] = av.w;
    #pragma unroll
    for (int j = 0; j < 4; j++) {
      int col = bc * 4 + j;
      Bs[brr][col] = (col < N) ? Bm[(size_t)(k0 + brr) * N + col] : 0.f;
    }
    __syncthreads();
    #pragma unroll
    for (int kk = 0; kk < GBK; kk++) {
      float4 a4 = *(const float4*)&As[kk][ty * 4];
      float4 b4 = *(const float4*)&Bs[kk][tx * 4];
      float a_[4] = {a4.x, a4.y, a4.z, a4.w};
      float b_[4] = {b4.x, b4.y, b4.z, b4.w};
      #pragma unroll
      for (int i = 0; i < 4; i++)
        #pragma unroll
        for (int j = 0; j < 4; j++)
          acc[i][j] += a_[i] * b_[j];
    }
    __syncthreads();
  }
  #pragma unroll
  for (int i = 0; i < 4; i++) {
    int row = m0 + ty * 4 + i;
    #pragma unroll
    for (int j = 0; j < 4; j++) {
      int col = tx * 4 + j;
      if (col < N) C[(size_t)row * N + col] = acc[i][j];
    }
  }
}

/* ---------------- per-head l2norm of f_q,f_k in place ---------------- */
__global__ __launch_bounds__(64) void l2norm_k() {
  int g = blockIdx.x;
  int lane = threadIdx.x;
  int h = g & (H_ - 1);
  int bt = g >> 4;
  size_t off = (size_t)bt * D_ + h * HD_ + lane;
  float qv = f_q[off];
  float s1 = qv * qv;
  #pragma unroll
  for (int o = 32; o > 0; o >>= 1) s1 += __shfl_xor(s1, o);
  f_q[off] = qv * rsqrtf(s1 + EPS_);
  float kv = f_k[off];
  float s2 = kv * kv;
  #pragma unroll
  for (int o = 32; o > 0; o >>= 1) s2 += __shfl_xor(s2, o);
  f_k[off] = kv * rsqrtf(s2 + EPS_);
}

/* ---------------- sigmoid(x + bias) in place ---------------- */
__global__ __launch_bounds__(256) void sigmoid_k(int id, float bias) {
  int i = blockIdx.x * 256 + threadIdx.x;
  float* p = fsel(id);
  float v = p[i] + bias;
  p[i] = 1.f / (1.f + expf(-v));
}

/* ---------------- gated delta rule scan (v2) -> b_o bf16 ---------------- */
#define CH 8
__device__ __forceinline__ void load_chunk(const float* kp, const float* qp,
    const float* vp, const float* bp, const float* ap, int t0, int kk,
    float2 (&kX)[CH], float2 (&qX)[CH], float (&vX)[CH], float (&bX)[CH],
    float (&aX)[CH]) {
  #pragma unroll
  for (int j = 0; j < CH; j++) {
    size_t tt = (size_t)(t0 + j);
    kX[j] = *(const float2*)(kp + tt * D_ + 2 * kk);
    qX[j] = *(const float2*)(qp + tt * D_ + 2 * kk);
    vX[j] = vp[tt * D_];
    bX[j] = bp[tt * H_];
    aX[j] = ap[tt * H_];
  }
}

__device__ __forceinline__ void steps_chunk(float2 (&kX)[CH], float2 (&qX)[CH],
    float (&vX)[CH], float (&bX)[CH], float (&aX)[CH], float& S0, float& S1,
    unsigned short* op, int t0, int kk) {
  #pragma unroll
  for (int j = 0; j < CH; j++) {
    float k0 = kX[j].x, k1 = kX[j].y, q0 = qX[j].x, q1 = qX[j].y;
    float al = aX[j], be = bX[j];
    float pk = S0 * k0 + S1 * k1;
    float pq = S0 * q0 + S1 * q1;
    float kq = k0 * q0 + k1 * q1;
    #pragma unroll
    for (int m = 1; m < 32; m <<= 1) {
      pk += __shfl_xor(pk, m);
      pq += __shfl_xor(pq, m);
      kq += __shfl_xor(kq, m);
    }
    float pred  = al * pk;
    float delta = be * (vX[j] - pred);
    float oo    = al * pq + kq * delta;
    S0 = al * S0 + k0 * delta;
    S1 = al * S1 + k1 * delta;
    if (kk == 0) op[(size_t)(t0 + j) * D_] = f2b(oo);
  }
}

__global__ __launch_bounds__(256) void scan2_k() {
  int tid = threadIdx.x;
  int gw = blockIdx.x * 4 + (tid >> 6);
  int lane = tid & 63;
  int vg = gw & 31;
  int bh = gw >> 5;
  int b = bh >> 4, h = bh & (H_ - 1);
  int kk = lane & 31;
  int c = vg * 2 + (lane >> 5);
  size_t kqbase = ((size_t)b * T_) * D_ + (size_t)h * HD_;
  const float* kp = f_k + kqbase;
  const float* qp = f_q + kqbase;
  const float* vp = f_v + kqbase + c;
  const float* bp = f_be + ((size_t)b * T_) * H_ + h;
  const float* ap = f_al + ((size_t)b * T_) * H_ + h;
  unsigned short* op = b_o + kqbase + c;

  float S0 = 0.f, S1 = 0.f;
  float2 kA[CH], qA[CH], kB[CH], qB[CH];
  float vA[CH], bA[CH], aA[CH], vB[CH], bB[CH], aB[CH];
  load_chunk(kp, qp, vp, bp, ap, 0, kk, kA, qA, vA, bA, aA);
  for (int t0 = 0; t0 < T_; t0 += 2 * CH) {
    load_chunk(kp, qp, vp, bp, ap, t0 + CH, kk, kB, qB, vB, bB, aB);
    steps_chunk(kA, qA, vA, bA, aA, S0, S1, op, t0, kk);
    if (t0 + 2 * CH < T_)
      load_chunk(kp, qp, vp, bp, ap, t0 + 2 * CH, kk, kA, qA, vA, bA, aA);
    steps_chunk(kB, qB, vB, bB, aB, S0, S1, op, t0 + CH, kk);
  }
}

/* ---------------- elementwise ---------------- */
__global__ __launch_bounds__(256) void add_h_k(const float* __restrict__ x) {
  int i = blockIdx.x * 256 + threadIdx.x;
  f_h[i] = x[i] + f_mix[i];
}
__global__ __launch_bounds__(256) void add_out_k(float* __restrict__ o) {
  int i = blockIdx.x * 256 + threadIdx.x;
  o[i] = f_h[i] + f_ffn[i];
}
__global__ __launch_bounds__(256) void swiglu2_k() {
  int col = blockIdx.x * 256 + threadIdx.x;
  size_t i = (size_t)blockIdx.y * IP_ + col;
  float x = f_g[i];
  float s = x / (1.f + expf(-x));
  b_f[i] = f2b(s * f_u[i]);
}

extern "C" void kernel_launch(void* const* d_in, const int* in_sizes, int n_in,
                              void* d_out, int out_size, void* d_ws, size_t ws_size,
                              hipStream_t stream) {
  const float* x   = (const float*)d_in[0];
  const float* n1w = (const float*)d_in[1];
  const float* n2w = (const float*)d_in[2];
  const float* cw  = (const float*)d_in[3];
  const float* cb  = (const float*)d_in[4];
  const float* wq  = (const float*)d_in[5];
  const float* wk  = (const float*)d_in[6];
  const float* wv  = (const float*)d_in[7];
  const float* wb  = (const float*)d_in[8];
  const float* wa  = (const float*)d_in[9];
  const float* wo  = (const float*)d_in[10];
  const float* wg  = (const float*)d_in[11];
  const float* wu  = (const float*)d_in[12];
  const float* wd  = (const float*)d_in[13];
  float* out = (float*)d_out;

  /* weight cast+transpose (bf16, padded) */
  castT_k<<<dim3(16, 16), 256, 0, stream>>>(wq, D_, D_, 4, D_, D_);
  castT_k<<<dim3(16, 16), 256, 0, stream>>>(wk, D_, D_, 5, D_, D_);
  castT_k<<<dim3(16, 16), 256, 0, stream>>>(wv, D_, D_, 6, D_, D_);
  castT_k<<<dim3(16, 16), 256, 0, stream>>>(wo, D_, D_, 7, D_, D_);
  castT_k<<<dim3(44, 16), 256, 0, stream>>>(wg, D_, I_, 8, D_, IP_);
  castT_k<<<dim3(44, 16), 256, 0, stream>>>(wu, D_, I_, 9, D_, IP_);
  castT_k<<<dim3(16, 44), 256, 0, stream>>>(wd, I_, D_, 10, IP_, D_);

  /* 1-2. norm1 + conv */
  rms1_k<<<BT_, 256, 0, stream>>>(x, n1w);
  conv2_k<<<ND_ / 256, 256, 0, stream>>>(cw, cb);
  /* 3. projections (bf16 MFMA) + gates (f32) */
  gemm_bf16<<<dim3(8, 32), 256, 0, stream>>>(0, 4, 0, D_, D_);   /* q */
  gemm_bf16<<<dim3(8, 32), 256, 0, stream>>>(0, 5, 1, D_, D_);   /* k */
  gemm_bf16<<<dim3(8, 32), 256, 0, stream>>>(0, 6, 2, D_, D_);   /* v */
  gemmba_k<<<dim3(1, 64), 256, 0, stream>>>(wb, 3);              /* beta  */
  gemmba_k<<<dim3(1, 64), 256, 0, stream>>>(wa, 4);              /* alpha */
  /* 4. l2norm + sigmoids */
  l2norm_k<<<NH_, 64, 0, stream>>>();
  sigmoid_k<<<NH_ / 256, 256, 0, stream>>>(3, 0.f);
  sigmoid_k<<<NH_ / 256, 256, 0, stream>>>(4, GATE_BIAS_);
  /* 5. scan -> b_o */
  scan2_k<<<256, 256, 0, stream>>>();
  /* 6-7. mix = o@wo ; h = x + mix */
  gemm_bf16<<<dim3(8, 32), 256, 0, stream>>>(1, 7, 5, D_, D_);
  add_h_k<<<ND_ / 256, 256, 0, stream>>>(x);
  /* 8. hn = rmsnorm(h) -> bf16 */
  rms2_k<<<BT_, 256, 0, stream>>>(n2w);
  /* 9. g,u */
  gemm_bf16<<<dim3(22, 32), 256, 0, stream>>>(2, 8, 6, D_, IP_);
  gemm_bf16<<<dim3(22, 32), 256, 0, stream>>>(2, 9, 7, D_, IP_);
  /* 10. f = silu(g)*u -> bf16 */
  swiglu2_k<<<dim3(IP_ / 256, BT_), 256, 0, stream>>>();
  /* 11. ffn = f@wd */
  gemm_bf16<<<dim3(8, 32), 256, 0, stream>>>(3, 10, 8, IP_, D_);
  /* 12. out = h + ffn */
  add_out_k<<<ND_ / 256, 256, 0, stream>>>(out);
}

// Round 4
// 1256.695 us; speedup vs baseline: 2.5356x; 1.0260x over previous
//
#include <hip/hip_runtime.h>
#include <math.h>

#define D_ 1024
#define H_ 16
#define HD_ 64
#define KW_ 4
#define I_ 2764
#define IP_ 2816              /* I padded to 22*128 */
#define B_ 2
#define T_ 2048
#define BT_ (B_*T_)           /* 4096 */
#define ND_ (BT_*D_)          /* 4194304 */
#define NIP_ (BT_*IP_)        /* 11534336 */
#define NH_ (BT_*H_)          /* 65536 */
#define NW_ (T_/8)            /* 256 windows per sequence */
#define EPS_ 1e-6f
#define GATE_BIAS_ 4.0f

typedef __attribute__((ext_vector_type(8))) short bf16x8;
typedef __attribute__((ext_vector_type(4))) float f32x4;

/* ---------------- static buffers ---------------- */
__device__ float f_xn[ND_];
__device__ float f_xc[ND_];
__device__ float f_q[ND_];
__device__ float f_k[ND_];
__device__ float f_v[ND_];
__device__ float f_be[NH_];
__device__ float f_al[NH_];
__device__ float f_mix[ND_];
__device__ float f_h[ND_];
__device__ float f_g[NIP_];
__device__ float f_u[NIP_];
__device__ float f_ffn[ND_];
__device__ float f_cross[32 * NW_ * 64];   /* packed per-window cross dots */
__device__ unsigned short b_xc[ND_];
__device__ unsigned short b_o[ND_];
__device__ unsigned short b_hn[ND_];
__device__ unsigned short b_f[NIP_];
__device__ unsigned short b_wqT[D_*D_];
__device__ unsigned short b_wkT[D_*D_];
__device__ unsigned short b_wvT[D_*D_];
__device__ unsigned short b_woT[D_*D_];
__device__ unsigned short b_wgT[IP_*D_];
__device__ unsigned short b_wuT[IP_*D_];
__device__ unsigned short b_wdT[(size_t)D_*IP_];

__device__ __forceinline__ unsigned short f2b(float x) {
  union { float f; unsigned u; } a; a.f = x;
  unsigned r = a.u + 0x7fff + ((a.u >> 16) & 1);
  return (unsigned short)(r >> 16);
}

__device__ __forceinline__ const unsigned short* bsel(int id) {
  switch (id) {
    case 0: return b_xc;  case 1: return b_o;   case 2: return b_hn;
    case 3: return b_f;   case 4: return b_wqT; case 5: return b_wkT;
    case 6: return b_wvT; case 7: return b_woT; case 8: return b_wgT;
    case 9: return b_wuT; default: return b_wdT;
  }
}
__device__ __forceinline__ unsigned short* bselw(int id) {
  return (unsigned short*)bsel(id);
}
__device__ __forceinline__ float* fsel(int id) {
  switch (id) {
    case 0: return f_q;  case 1: return f_k;   case 2: return f_v;
    case 3: return f_be; case 4: return f_al;  case 5: return f_mix;
    case 6: return f_g;  case 7: return f_u;   default: return f_ffn;
  }
}

/* ---------------- RMSNorm 1: f_xn = rms(x)*w ---------------- */
__global__ __launch_bounds__(256) void rms1_k(const float* __restrict__ x,
                                              const float* __restrict__ w) {
  int row = blockIdx.x;
  const float* xr = x + (size_t)row * D_;
  int tid = threadIdx.x;
  float4 v = ((const float4*)xr)[tid];
  float ss = v.x*v.x + v.y*v.y + v.z*v.z + v.w*v.w;
  #pragma unroll
  for (int o = 32; o > 0; o >>= 1) ss += __shfl_down(ss, o);
  __shared__ float sred[4];
  __shared__ float sscale;
  if ((tid & 63) == 0) sred[tid >> 6] = ss;
  __syncthreads();
  if (tid == 0)
    sscale = rsqrtf((sred[0]+sred[1]+sred[2]+sred[3]) / (float)D_ + EPS_);
  __syncthreads();
  float s = sscale;
  float4 wv = ((const float4*)w)[tid];
  float4 o;
  o.x = v.x*s*wv.x; o.y = v.y*s*wv.y; o.z = v.z*s*wv.z; o.w = v.w*s*wv.w;
  ((float4*)(f_xn + (size_t)row * D_))[tid] = o;
}

/* ---------------- RMSNorm 2: b_hn = bf16(rms(f_h)*w) ---------------- */
__global__ __launch_bounds__(256) void rms2_k(const float* __restrict__ w) {
  int row = blockIdx.x;
  const float* xr = f_h + (size_t)row * D_;
  int tid = threadIdx.x;
  float4 v = ((const float4*)xr)[tid];
  float ss = v.x*v.x + v.y*v.y + v.z*v.z + v.w*v.w;
  #pragma unroll
  for (int o = 32; o > 0; o >>= 1) ss += __shfl_down(ss, o);
  __shared__ float sred[4];
  __shared__ float sscale;
  if ((tid & 63) == 0) sred[tid >> 6] = ss;
  __syncthreads();
  if (tid == 0)
    sscale = rsqrtf((sred[0]+sred[1]+sred[2]+sred[3]) / (float)D_ + EPS_);
  __syncthreads();
  float s = sscale;
  float4 wv = ((const float4*)w)[tid];
  unsigned short* orow = b_hn + (size_t)row * D_ + tid * 4;
  orow[0] = f2b(v.x*s*wv.x); orow[1] = f2b(v.y*s*wv.y);
  orow[2] = f2b(v.z*s*wv.z); orow[3] = f2b(v.w*s*wv.w);
}

/* ---------------- causal depthwise conv + SiLU -> f_xc, b_xc ---------------- */
__global__ __launch_bounds__(256) void conv2_k(const float* __restrict__ cw,
                                               const float* __restrict__ cb) {
  int idx = blockIdx.x * 256 + threadIdx.x;
  int d = idx & (D_ - 1);
  int bt = idx >> 10;
  int t = bt & (T_ - 1);
  float acc = cb[d];
  #pragma unroll
  for (int j = 0; j < KW_; j++) {
    int tt = t - (KW_ - 1) + j;
    if (tt >= 0) acc += f_xn[(size_t)idx + (size_t)(j - (KW_-1)) * D_] * cw[d * KW_ + j];
  }
  float s = acc / (1.f + expf(-acc));
  f_xc[idx] = s;
  b_xc[idx] = f2b(s);
}

/* ---------------- weight cast + transpose: W[K][N] f32 -> out[Np][Kp] bf16 ---------------- */
__global__ __launch_bounds__(256) void castT_k(const float* __restrict__ W,
                                               int K, int N, int outid,
                                               int Kp, int Np) {
  __shared__ float s[64][65];
  unsigned short* out = bselw(outid);
  int k0 = blockIdx.y * 64, n0 = blockIdx.x * 64;
  int tx = threadIdx.x & 63, ty = threadIdx.x >> 6;
  #pragma unroll
  for (int j = ty; j < 64; j += 4) {
    int kk = k0 + j, nn = n0 + tx;
    s[j][tx] = (kk < K && nn < N) ? W[(size_t)kk * N + nn] : 0.f;
  }
  __syncthreads();
  #pragma unroll
  for (int j = ty; j < 64; j += 4) {
    int nn = n0 + j, kk = k0 + tx;
    out[(size_t)nn * Kp + kk] = f2b(s[tx][j]);
  }
}

/* ---------------- bf16 MFMA GEMM (128x128 tile, BK=32) ---------------- */
__global__ __launch_bounds__(256) void gemm_bf16(int aid, int bid, int cid,
                                                 int Kp, int ldc) {
  __shared__ __align__(16) unsigned short Al[128 * 32];
  __shared__ __align__(16) unsigned short Bl[128 * 32];
  const unsigned short* A = bsel(aid);
  const unsigned short* Bt = bsel(bid);
  float* C = fsel(cid);
  int tid = threadIdx.x;
  int m0 = blockIdx.y * 128, n0 = blockIdx.x * 128;
  int wave = tid >> 6, lane = tid & 63;
  int wm = (wave >> 1) * 64, wn = (wave & 1) * 64;
  int lrow = tid >> 2;
  int lcol = (tid & 3) * 8;
  f32x4 acc[4][4] = {};
  const int l15 = lane & 15, lg = lane >> 4;
  for (int k0 = 0; k0 < Kp; k0 += 32) {
    const unsigned short* Ag = A + (size_t)m0 * Kp + k0;
    const unsigned short* Bg = Bt + (size_t)n0 * Kp + k0;
    __builtin_amdgcn_global_load_lds(
      (const __attribute__((address_space(1))) void*)(Ag + (size_t)lrow * Kp + lcol),
      (__attribute__((address_space(3))) void*)(Al + wave * 512), 16, 0, 0);
    __builtin_amdgcn_global_load_lds(
      (const __attribute__((address_space(1))) void*)(Ag + (size_t)(64 + lrow) * Kp + lcol),
      (__attribute__((address_space(3))) void*)(Al + 2048 + wave * 512), 16, 0, 0);
    __builtin_amdgcn_global_load_lds(
      (const __attribute__((address_space(1))) void*)(Bg + (size_t)lrow * Kp + lcol),
      (__attribute__((address_space(3))) void*)(Bl + wave * 512), 16, 0, 0);
    __builtin_amdgcn_global_load_lds(
      (const __attribute__((address_space(1))) void*)(Bg + (size_t)(64 + lrow) * Kp + lcol),
      (__attribute__((address_space(3))) void*)(Bl + 2048 + wave * 512), 16, 0, 0);
    __syncthreads();
    bf16x8 af[4], bf[4];
    #pragma unroll
    for (int i = 0; i < 4; i++)
      af[i] = *(const bf16x8*)&Al[(wm + i * 16 + l15) * 32 + lg * 8];
    #pragma unroll
    for (int j = 0; j < 4; j++)
      bf[j] = *(const bf16x8*)&Bl[(wn + j * 16 + l15) * 32 + lg * 8];
    #pragma unroll
    for (int i = 0; i < 4; i++)
      #pragma unroll
      for (int j = 0; j < 4; j++)
        acc[i][j] = __builtin_amdgcn_mfma_f32_16x16x32_bf16(af[i], bf[j], acc[i][j], 0, 0, 0);
    __syncthreads();
  }
  #pragma unroll
  for (int i = 0; i < 4; i++) {
    int r0 = m0 + wm + i * 16 + lg * 4;
    #pragma unroll
    for (int j = 0; j < 4; j++) {
      int cc = n0 + wn + j * 16 + l15;
      #pragma unroll
      for (int r = 0; r < 4; r++)
        C[(size_t)(r0 + r) * ldc + cc] = acc[i][j][r];
    }
  }
}

/* ---------------- small f32 GEMM for beta/alpha ---------------- */
#define GBM 64
#define GBN 64
#define GBK 16
__global__ __launch_bounds__(256) void gemmba_k(const float* __restrict__ Bm, int cid) {
  __shared__ float As[GBK][GBM + 4];
  __shared__ float Bs[GBK][GBN + 4];
  const int N = H_, Kd = D_;
  float* C = fsel(cid);
  int tid = threadIdx.x;
  int m0 = blockIdx.y * GBM;
  int ty = tid >> 4, tx = tid & 15;
  int ar = tid >> 2, aq = tid & 3;
  int brr = tid >> 4, bc = tid & 15;
  float acc[4][4] = {};
  for (int k0 = 0; k0 < Kd; k0 += GBK) {
    float4 av = *(const float4*)(f_xc + (size_t)(m0 + ar) * Kd + k0 + aq * 4);
    As[aq*4+0][ar] = av.x; As[aq*4+1][ar] = av.y;
    As[aq*4+2][ar] = av.z; As[aq*4+3][ar] = av.w;
    #pragma unroll
    for (int j = 0; j < 4; j++) {
      int col = bc * 4 + j;
      Bs[brr][col] = (col < N) ? Bm[(size_t)(k0 + brr) * N + col] : 0.f;
    }
    __syncthreads();
    #pragma unroll
    for (int kk = 0; kk < GBK; kk++) {
      float4 a4 = *(const float4*)&As[kk][ty * 4];
      float4 b4 = *(const float4*)&Bs[kk][tx * 4];
      float a_[4] = {a4.x, a4.y, a4.z, a4.w};
      float b_[4] = {b4.x, b4.y, b4.z, b4.w};
      #pragma unroll
      for (int i = 0; i < 4; i++)
        #pragma unroll
        for (int j = 0; j < 4; j++)
          acc[i][j] += a_[i] * b_[j];
    }
    __syncthreads();
  }
  #pragma unroll
  for (int i = 0; i < 4; i++) {
    int row = m0 + ty * 4 + i;
    #pragma unroll
    for (int j = 0; j < 4; j++) {
      int col = tx * 4 + j;
      if (col < N) C[(size_t)row * N + col] = acc[i][j];
    }
  }
}

/* ---------------- per-head l2norm of f_q,f_k in place ---------------- */
__global__ __launch_bounds__(64) void l2norm_k() {
  int g = blockIdx.x;
  int lane = threadIdx.x;
  int h = g & (H_ - 1);
  int bt = g >> 4;
  size_t off = (size_t)bt * D_ + h * HD_ + lane;
  float qv = f_q[off];
  float s1 = qv * qv;
  #pragma unroll
  for (int o = 32; o > 0; o >>= 1) s1 += __shfl_xor(s1, o);
  f_q[off] = qv * rsqrtf(s1 + EPS_);
  float kv = f_k[off];
  float s2 = kv * kv;
  #pragma unroll
  for (int o = 32; o > 0; o >>= 1) s2 += __shfl_xor(s2, o);
  f_k[off] = kv * rsqrtf(s2 + EPS_);
}

/* ---------------- sigmoid(x + bias) in place ---------------- */
__global__ __launch_bounds__(256) void sigmoid_k(int id, float bias) {
  int i = blockIdx.x * 256 + threadIdx.x;
  float* p = fsel(id);
  float v = p[i] + bias;
  p[i] = 1.f / (1.f + expf(-v));
}

/* ---------------- cross-dot precompute: per (bh, window of 8 steps) ----------------
 * lane l: j = l>>3, r = l&7.  ckk(j,r)=k_j.k_r stored (j<r) at r(r-1)/2+j;
 * cqk(j,r)=k_j.q_r stored (j<=r) at 28 + r(r+1)/2+j.  64 slots exactly.  */
__global__ __launch_bounds__(64) void crossdot_k() {
  __shared__ float sK[8][65];
  __shared__ float sQ[8][65];
  int gid = blockIdx.x;              /* bh*NW_ + w */
  int w = gid & (NW_ - 1);
  int bh = gid >> 8;
  int b = bh >> 4, h = bh & (H_ - 1);
  int lane = threadIdx.x;
  size_t base = ((size_t)(b * T_ + w * 8)) * D_ + h * HD_;
  #pragma unroll
  for (int j = 0; j < 8; j++) {
    sK[j][lane] = f_k[base + (size_t)j * D_ + lane];
    sQ[j][lane] = f_q[base + (size_t)j * D_ + lane];
  }
  __syncthreads();
  int j = lane >> 3, r = lane & 7;
  float ck = 0.f, cq = 0.f;
  #pragma unroll
  for (int t = 0; t < 64; t++) {
    float kj = sK[j][t];
    ck += kj * sK[r][t];
    cq += kj * sQ[r][t];
  }
  float* outp = f_cross + (size_t)gid * 64;
  if (j < r)  outp[r * (r - 1) / 2 + j] = ck;
  if (j <= r) outp[28 + r * (r + 1) / 2 + j] = cq;
}

/* ---------------- gated delta rule scan v3: 8-step windowed mini-WY ----------------
 * chain = one column of one (b,h); 32 lanes per chain (2 k-elems per lane).
 * Per window: 16 base dots vs entering S -> ONE 5-level butterfly; cross dots
 * precomputed; lane-redundant 8x8 forward substitution; S update.            */
#define CH 8
#define CKK(j,r) cxv[((r)*((r)-1)/2+(j))>>2][((r)*((r)-1)/2+(j))&3]
#define CQK(j,r) cxv[(28+(r)*((r)+1)/2+(j))>>2][(28+(r)*((r)+1)/2+(j))&3]

__device__ __forceinline__ void load_chunk(const float* kp, const float* qp,
    const float* vp, const float* bp, const float* ap, int t0, int kk,
    float2 (&kX)[CH], float2 (&qX)[CH], float (&vX)[CH], float (&bX)[CH],
    float (&aX)[CH]) {
  #pragma unroll
  for (int j = 0; j < CH; j++) {
    size_t tt = (size_t)(t0 + j);
    kX[j] = *(const float2*)(kp + tt * D_ + 2 * kk);
    qX[j] = *(const float2*)(qp + tt * D_ + 2 * kk);
    vX[j] = vp[tt * D_];
    bX[j] = bp[tt * H_];
    aX[j] = ap[tt * H_];
  }
}

__device__ __forceinline__ void window8(float2 (&kX)[CH], float2 (&qX)[CH],
    float (&vX)[CH], float (&bX)[CH], float (&aX)[CH], float& S0, float& S1,
    unsigned short* op, const float* cp, int t0, int kk) {
  /* base dot partials vs entering S */
  float PK[8], PQ[8];
  #pragma unroll
  for (int j = 0; j < 8; j++) {
    PK[j] = S0 * kX[j].x + S1 * kX[j].y;
    PQ[j] = S0 * qX[j].x + S1 * qX[j].y;
  }
  /* issue cross-dot loads (consumed after butterfly -> latency hidden) */
  f32x4 cxv[16];
  #pragma unroll
  for (int i = 0; i < 16; i++)
    cxv[i] = *(const f32x4*)(cp + i * 4);
  /* one butterfly for all 16 values (masks stay inside 32-lane half) */
  #pragma unroll
  for (int m = 1; m < 32; m <<= 1) {
    #pragma unroll
    for (int j = 0; j < 8; j++) {
      PK[j] += __shfl_xor(PK[j], m);
      PQ[j] += __shfl_xor(PQ[j], m);
    }
  }
  /* cumulative decay + reciprocals */
  float gm[8], ig[8];
  gm[0] = aX[0];
  #pragma unroll
  for (int r = 1; r < 8; r++) gm[r] = gm[r-1] * aX[r];
  #pragma unroll
  for (int r = 0; r < 8; r++) ig[r] = __builtin_amdgcn_rcpf(gm[r]);
  /* forward substitution (lane-redundant) */
  float us[8];
  #pragma unroll
  for (int r = 0; r < 8; r++) {
    float pred = PK[r];
    #pragma unroll
    for (int j = 0; j < r; j++) pred = fmaf(CKK(j, r), us[j], pred);
    pred *= gm[r];
    float uu = bX[r] * (vX[r] - pred);
    us[r] = uu * ig[r];
    float oa = PQ[r];
    #pragma unroll
    for (int j = 0; j <= r; j++) oa = fmaf(CQK(j, r), us[j], oa);
    if (kk == 0) op[(size_t)(t0 + r) * D_] = f2b(gm[r] * oa);
  }
  /* state update: S = gm7 * (S + sum_j k_j * us_j) */
  float a0 = 0.f, a1 = 0.f;
  #pragma unroll
  for (int j = 0; j < 8; j++) {
    a0 = fmaf(kX[j].x, us[j], a0);
    a1 = fmaf(kX[j].y, us[j], a1);
  }
  S0 = gm[7] * (S0 + a0);
  S1 = gm[7] * (S1 + a1);
}

__global__ __launch_bounds__(256, 1) void scan3_k() {
  int tid = threadIdx.x;
  int gw = blockIdx.x * 4 + (tid >> 6);   /* 0..1023 */
  int lane = tid & 63;
  int vg = gw & 31;
  int bh = gw >> 5;
  int b = bh >> 4, h = bh & (H_ - 1);
  int kk = lane & 31;
  int c = vg * 2 + (lane >> 5);
  size_t kqbase = ((size_t)b * T_) * D_ + (size_t)h * HD_;
  const float* kp = f_k + kqbase;
  const float* qp = f_q + kqbase;
  const float* vp = f_v + kqbase + c;
  const float* bp = f_be + ((size_t)b * T_) * H_ + h;
  const float* ap = f_al + ((size_t)b * T_) * H_ + h;
  const float* crbase = f_cross + (size_t)bh * NW_ * 64;
  unsigned short* op = b_o + kqbase + c;

  float S0 = 0.f, S1 = 0.f;
  float2 kA[CH], qA[CH], kB[CH], qB[CH];
  float vA[CH], bA[CH], aA[CH], vB[CH], bB[CH], aB[CH];
  load_chunk(kp, qp, vp, bp, ap, 0, kk, kA, qA, vA, bA, aA);
  for (int t0 = 0; t0 < T_; t0 += 2 * CH) {
    load_chunk(kp, qp, vp, bp, ap, t0 + CH, kk, kB, qB, vB, bB, aB);
    window8(kA, qA, vA, bA, aA, S0, S1, op, crbase + (size_t)(t0 >> 3) * 64, t0, kk);
    if (t0 + 2 * CH < T_)
      load_chunk(kp, qp, vp, bp, ap, t0 + 2 * CH, kk, kA, qA, vA, bA, aA);
    window8(kB, qB, vB, bB, aB, S0, S1, op, crbase + (size_t)((t0 >> 3) + 1) * 64,
            t0 + CH, kk);
  }
}

/* ---------------- elementwise ---------------- */
__global__ __launch_bounds__(256) void add_h_k(const float* __restrict__ x) {
  int i = blockIdx.x * 256 + threadIdx.x;
  f_h[i] = x[i] + f_mix[i];
}
__global__ __launch_bounds__(256) void add_out_k(float* __restrict__ o) {
  int i = blockIdx.x * 256 + threadIdx.x;
  o[i] = f_h[i] + f_ffn[i];
}
__global__ __launch_bounds__(256) void swiglu2_k() {
  int col = blockIdx.x * 256 + threadIdx.x;
  size_t i = (size_t)blockIdx.y * IP_ + col;
  float x = f_g[i];
  float s = x / (1.f + expf(-x));
  b_f[i] = f2b(s * f_u[i]);
}

extern "C" void kernel_launch(void* const* d_in, const int* in_sizes, int n_in,
                              void* d_out, int out_size, void* d_ws, size_t ws_size,
                              hipStream_t stream) {
  const float* x   = (const float*)d_in[0];
  const float* n1w = (const float*)d_in[1];
  const float* n2w = (const float*)d_in[2];
  const float* cw  = (const float*)d_in[3];
  const float* cb  = (const float*)d_in[4];
  const float* wq  = (const float*)d_in[5];
  const float* wk  = (const float*)d_in[6];
  const float* wv  = (const float*)d_in[7];
  const float* wb  = (const float*)d_in[8];
  const float* wa  = (const float*)d_in[9];
  const float* wo  = (const float*)d_in[10];
  const float* wg  = (const float*)d_in[11];
  const float* wu  = (const float*)d_in[12];
  const float* wd  = (const float*)d_in[13];
  float* out = (float*)d_out;

  /* weight cast+transpose (bf16, padded) */
  castT_k<<<dim3(16, 16), 256, 0, stream>>>(wq, D_, D_, 4, D_, D_);
  castT_k<<<dim3(16, 16), 256, 0, stream>>>(wk, D_, D_, 5, D_, D_);
  castT_k<<<dim3(16, 16), 256, 0, stream>>>(wv, D_, D_, 6, D_, D_);
  castT_k<<<dim3(16, 16), 256, 0, stream>>>(wo, D_, D_, 7, D_, D_);
  castT_k<<<dim3(44, 16), 256, 0, stream>>>(wg, D_, I_, 8, D_, IP_);
  castT_k<<<dim3(44, 16), 256, 0, stream>>>(wu, D_, I_, 9, D_, IP_);
  castT_k<<<dim3(16, 44), 256, 0, stream>>>(wd, I_, D_, 10, IP_, D_);

  /* 1-2. norm1 + conv */
  rms1_k<<<BT_, 256, 0, stream>>>(x, n1w);
  conv2_k<<<ND_ / 256, 256, 0, stream>>>(cw, cb);
  /* 3. projections (bf16 MFMA) + gates (f32) */
  gemm_bf16<<<dim3(8, 32), 256, 0, stream>>>(0, 4, 0, D_, D_);   /* q */
  gemm_bf16<<<dim3(8, 32), 256, 0, stream>>>(0, 5, 1, D_, D_);   /* k */
  gemm_bf16<<<dim3(8, 32), 256, 0, stream>>>(0, 6, 2, D_, D_);   /* v */
  gemmba_k<<<dim3(1, 64), 256, 0, stream>>>(wb, 3);              /* beta  */
  gemmba_k<<<dim3(1, 64), 256, 0, stream>>>(wa, 4);              /* alpha */
  /* 4. l2norm + sigmoids + cross dots */
  l2norm_k<<<NH_, 64, 0, stream>>>();
  sigmoid_k<<<NH_ / 256, 256, 0, stream>>>(3, 0.f);
  sigmoid_k<<<NH_ / 256, 256, 0, stream>>>(4, GATE_BIAS_);
  crossdot_k<<<32 * NW_, 64, 0, stream>>>();
  /* 5. scan -> b_o */
  scan3_k<<<256, 256, 0, stream>>>();
  /* 6-7. mix = o@wo ; h = x + mix */
  gemm_bf16<<<dim3(8, 32), 256, 0, stream>>>(1, 7, 5, D_, D_);
  add_h_k<<<ND_ / 256, 256, 0, stream>>>(x);
  /* 8. hn = rmsnorm(h) -> bf16 */
  rms2_k<<<BT_, 256, 0, stream>>>(n2w);
  /* 9. g,u */
  gemm_bf16<<<dim3(22, 32), 256, 0, stream>>>(2, 8, 6, D_, IP_);
  gemm_bf16<<<dim3(22, 32), 256, 0, stream>>>(2, 9, 7, D_, IP_);
  /* 10. f = silu(g)*u -> bf16 */
  swiglu2_k<<<dim3(IP_ / 256, BT_), 256, 0, stream>>>();
  /* 11. ffn = f@wd */
  gemm_bf16<<<dim3(8, 32), 256, 0, stream>>>(3, 10, 8, IP_, D_);
  /* 12. out = h + ffn */
  add_out_k<<<ND_ / 256, 256, 0, stream>>>(out);
}

// Round 5
// 944.603 us; speedup vs baseline: 3.3733x; 1.3304x over previous
//
#include <hip/hip_runtime.h>
#include <math.h>

#define D_ 1024
#define H_ 16
#define HD_ 64
#define KW_ 4
#define I_ 2764
#define IP_ 2816              /* I padded to 22*128 */
#define B_ 2
#define T_ 2048
#define BT_ (B_*T_)           /* 4096 */
#define ND_ (BT_*D_)          /* 4194304 */
#define NIP_ (BT_*IP_)        /* 11534336 */
#define NH_ (BT_*H_)          /* 65536 */
#define NCH_ 32               /* chunks per sequence (T/64) */
#define NG_ (32*NCH_)         /* 1024 (bh,chunk) groups */
#define EPS_ 1e-6f
#define GATE_BIAS_ 4.0f

typedef __attribute__((ext_vector_type(8))) short bf16x8;
typedef __attribute__((ext_vector_type(4))) float f32x4;

/* ---------------- static buffers ---------------- */
__device__ float f_xn[ND_];
__device__ float f_xc[ND_];
__device__ float f_q[ND_];
__device__ float f_k[ND_];
__device__ float f_v[ND_];
__device__ float f_be[NH_];
__device__ float f_al[NH_];
__device__ float f_mix[ND_];
__device__ float f_h[ND_];
__device__ float f_g[NIP_];
__device__ float f_u[NIP_];
__device__ float f_ffn[ND_];
__device__ float g_rs[NG_ * 256];                 /* per (g,t): b, b*gam, gam, - */
__device__ unsigned short g_Tinv[(size_t)NG_*4096];
__device__ unsigned short g_Gqk[(size_t)NG_*4096];
__device__ unsigned short g_KdT[(size_t)NG_*4096];
__device__ unsigned short b_xc[ND_];
__device__ unsigned short b_o[ND_];
__device__ unsigned short b_hn[ND_];
__device__ unsigned short b_f[NIP_];
__device__ unsigned short b_wqT[D_*D_];
__device__ unsigned short b_wkT[D_*D_];
__device__ unsigned short b_wvT[D_*D_];
__device__ unsigned short b_woT[D_*D_];
__device__ unsigned short b_wgT[IP_*D_];
__device__ unsigned short b_wuT[IP_*D_];
__device__ unsigned short b_wdT[(size_t)D_*IP_];

__device__ __forceinline__ unsigned short f2b(float x) {
  union { float f; unsigned u; } a; a.f = x;
  unsigned r = a.u + 0x7fff + ((a.u >> 16) & 1);
  return (unsigned short)(r >> 16);
}
__device__ __forceinline__ float b2f(unsigned short s) {
  union { unsigned u; float f; } a; a.u = ((unsigned)s) << 16; return a.f;
}
__device__ __forceinline__ bf16x8 cvt8(float4 a, float4 b) {
  bf16x8 r;
  r[0] = (short)f2b(a.x); r[1] = (short)f2b(a.y);
  r[2] = (short)f2b(a.z); r[3] = (short)f2b(a.w);
  r[4] = (short)f2b(b.x); r[5] = (short)f2b(b.y);
  r[6] = (short)f2b(b.z); r[7] = (short)f2b(b.w);
  return r;
}

__device__ __forceinline__ const unsigned short* bsel(int id) {
  switch (id) {
    case 0: return b_xc;  case 1: return b_o;   case 2: return b_hn;
    case 3: return b_f;   case 4: return b_wqT; case 5: return b_wkT;
    case 6: return b_wvT; case 7: return b_woT; case 8: return b_wgT;
    case 9: return b_wuT; default: return b_wdT;
  }
}
__device__ __forceinline__ unsigned short* bselw(int id) {
  return (unsigned short*)bsel(id);
}
__device__ __forceinline__ float* fsel(int id) {
  switch (id) {
    case 0: return f_q;  case 1: return f_k;   case 2: return f_v;
    case 3: return f_be; case 4: return f_al;  case 5: return f_mix;
    case 6: return f_g;  case 7: return f_u;   default: return f_ffn;
  }
}

/* ---------------- RMSNorm 1 ---------------- */
__global__ __launch_bounds__(256) void rms1_k(const float* __restrict__ x,
                                              const float* __restrict__ w) {
  int row = blockIdx.x;
  const float* xr = x + (size_t)row * D_;
  int tid = threadIdx.x;
  float4 v = ((const float4*)xr)[tid];
  float ss = v.x*v.x + v.y*v.y + v.z*v.z + v.w*v.w;
  #pragma unroll
  for (int o = 32; o > 0; o >>= 1) ss += __shfl_down(ss, o);
  __shared__ float sred[4];
  __shared__ float sscale;
  if ((tid & 63) == 0) sred[tid >> 6] = ss;
  __syncthreads();
  if (tid == 0)
    sscale = rsqrtf((sred[0]+sred[1]+sred[2]+sred[3]) / (float)D_ + EPS_);
  __syncthreads();
  float s = sscale;
  float4 wv = ((const float4*)w)[tid];
  float4 o;
  o.x = v.x*s*wv.x; o.y = v.y*s*wv.y; o.z = v.z*s*wv.z; o.w = v.w*s*wv.w;
  ((float4*)(f_xn + (size_t)row * D_))[tid] = o;
}

/* ---------------- RMSNorm 2 -> bf16 ---------------- */
__global__ __launch_bounds__(256) void rms2_k(const float* __restrict__ w) {
  int row = blockIdx.x;
  const float* xr = f_h + (size_t)row * D_;
  int tid = threadIdx.x;
  float4 v = ((const float4*)xr)[tid];
  float ss = v.x*v.x + v.y*v.y + v.z*v.z + v.w*v.w;
  #pragma unroll
  for (int o = 32; o > 0; o >>= 1) ss += __shfl_down(ss, o);
  __shared__ float sred[4];
  __shared__ float sscale;
  if ((tid & 63) == 0) sred[tid >> 6] = ss;
  __syncthreads();
  if (tid == 0)
    sscale = rsqrtf((sred[0]+sred[1]+sred[2]+sred[3]) / (float)D_ + EPS_);
  __syncthreads();
  float s = sscale;
  float4 wv = ((const float4*)w)[tid];
  unsigned short* orow = b_hn + (size_t)row * D_ + tid * 4;
  orow[0] = f2b(v.x*s*wv.x); orow[1] = f2b(v.y*s*wv.y);
  orow[2] = f2b(v.z*s*wv.z); orow[3] = f2b(v.w*s*wv.w);
}

/* ---------------- causal depthwise conv + SiLU ---------------- */
__global__ __launch_bounds__(256) void conv2_k(const float* __restrict__ cw,
                                               const float* __restrict__ cb) {
  int idx = blockIdx.x * 256 + threadIdx.x;
  int d = idx & (D_ - 1);
  int bt = idx >> 10;
  int t = bt & (T_ - 1);
  float acc = cb[d];
  #pragma unroll
  for (int j = 0; j < KW_; j++) {
    int tt = t - (KW_ - 1) + j;
    if (tt >= 0) acc += f_xn[(size_t)idx + (size_t)(j - (KW_-1)) * D_] * cw[d * KW_ + j];
  }
  float s = acc / (1.f + expf(-acc));
  f_xc[idx] = s;
  b_xc[idx] = f2b(s);
}

/* ---------------- weight cast + transpose ---------------- */
__global__ __launch_bounds__(256) void castT_k(const float* __restrict__ W,
                                               int K, int N, int outid,
                                               int Kp, int Np) {
  __shared__ float s[64][65];
  unsigned short* out = bselw(outid);
  int k0 = blockIdx.y * 64, n0 = blockIdx.x * 64;
  int tx = threadIdx.x & 63, ty = threadIdx.x >> 6;
  #pragma unroll
  for (int j = ty; j < 64; j += 4) {
    int kk = k0 + j, nn = n0 + tx;
    s[j][tx] = (kk < K && nn < N) ? W[(size_t)kk * N + nn] : 0.f;
  }
  __syncthreads();
  #pragma unroll
  for (int j = ty; j < 64; j += 4) {
    int nn = n0 + j, kk = k0 + tx;
    out[(size_t)nn * Kp + kk] = f2b(s[tx][j]);
  }
}

/* ---------------- bf16 MFMA GEMM (128x128 tile, BK=32) ---------------- */
__global__ __launch_bounds__(256) void gemm_bf16(int aid, int bid, int cid,
                                                 int Kp, int ldc) {
  __shared__ __align__(16) unsigned short Al[128 * 32];
  __shared__ __align__(16) unsigned short Bl[128 * 32];
  const unsigned short* A = bsel(aid);
  const unsigned short* Bt = bsel(bid);
  float* C = fsel(cid);
  int tid = threadIdx.x;
  int m0 = blockIdx.y * 128, n0 = blockIdx.x * 128;
  int wave = tid >> 6, lane = tid & 63;
  int wm = (wave >> 1) * 64, wn = (wave & 1) * 64;
  int lrow = tid >> 2;
  int lcol = (tid & 3) * 8;
  f32x4 acc[4][4] = {};
  const int l15 = lane & 15, lg = lane >> 4;
  for (int k0 = 0; k0 < Kp; k0 += 32) {
    const unsigned short* Ag = A + (size_t)m0 * Kp + k0;
    const unsigned short* Bg = Bt + (size_t)n0 * Kp + k0;
    __builtin_amdgcn_global_load_lds(
      (const __attribute__((address_space(1))) void*)(Ag + (size_t)lrow * Kp + lcol),
      (__attribute__((address_space(3))) void*)(Al + wave * 512), 16, 0, 0);
    __builtin_amdgcn_global_load_lds(
      (const __attribute__((address_space(1))) void*)(Ag + (size_t)(64 + lrow) * Kp + lcol),
      (__attribute__((address_space(3))) void*)(Al + 2048 + wave * 512), 16, 0, 0);
    __builtin_amdgcn_global_load_lds(
      (const __attribute__((address_space(1))) void*)(Bg + (size_t)lrow * Kp + lcol),
      (__attribute__((address_space(3))) void*)(Bl + wave * 512), 16, 0, 0);
    __builtin_amdgcn_global_load_lds(
      (const __attribute__((address_space(1))) void*)(Bg + (size_t)(64 + lrow) * Kp + lcol),
      (__attribute__((address_space(3))) void*)(Bl + 2048 + wave * 512), 16, 0, 0);
    __syncthreads();
    bf16x8 af[4], bf[4];
    #pragma unroll
    for (int i = 0; i < 4; i++)
      af[i] = *(const bf16x8*)&Al[(wm + i * 16 + l15) * 32 + lg * 8];
    #pragma unroll
    for (int j = 0; j < 4; j++)
      bf[j] = *(const bf16x8*)&Bl[(wn + j * 16 + l15) * 32 + lg * 8];
    #pragma unroll
    for (int i = 0; i < 4; i++)
      #pragma unroll
      for (int j = 0; j < 4; j++)
        acc[i][j] = __builtin_amdgcn_mfma_f32_16x16x32_bf16(af[i], bf[j], acc[i][j], 0, 0, 0);
    __syncthreads();
  }
  #pragma unroll
  for (int i = 0; i < 4; i++) {
    int r0 = m0 + wm + i * 16 + lg * 4;
    #pragma unroll
    for (int j = 0; j < 4; j++) {
      int cc = n0 + wn + j * 16 + l15;
      #pragma unroll
      for (int r = 0; r < 4; r++)
        C[(size_t)(r0 + r) * ldc + cc] = acc[i][j][r];
    }
  }
}

/* ---------------- small f32 GEMM for beta/alpha ---------------- */
#define GBM 64
#define GBK 16
__global__ __launch_bounds__(256) void gemmba_k(const float* __restrict__ Bm, int cid) {
  __shared__ float As[GBK][GBM + 4];
  __shared__ float Bs[GBK][64 + 4];
  const int N = H_, Kd = D_;
  float* C = fsel(cid);
  int tid = threadIdx.x;
  int m0 = blockIdx.y * GBM;
  int ty = tid >> 4, tx = tid & 15;
  int ar = tid >> 2, aq = tid & 3;
  int brr = tid >> 4, bc = tid & 15;
  float acc[4][4] = {};
  for (int k0 = 0; k0 < Kd; k0 += GBK) {
    float4 av = *(const float4*)(f_xc + (size_t)(m0 + ar) * Kd + k0 + aq * 4);
    As[aq*4+0][ar] = av.x; As[aq*4+1][ar] = av.y;
    As[aq*4+2][ar] = av.z; As[aq*4+3][ar] = av.w;
    #pragma unroll
    for (int j = 0; j < 4; j++) {
      int col = bc * 4 + j;
      Bs[brr][col] = (col < N) ? Bm[(size_t)(k0 + brr) * N + col] : 0.f;
    }
    __syncthreads();
    #pragma unroll
    for (int kk = 0; kk < GBK; kk++) {
      float4 a4 = *(const float4*)&As[kk][ty * 4];
      float4 b4 = *(const float4*)&Bs[kk][tx * 4];
      float a_[4] = {a4.x, a4.y, a4.z, a4.w};
      float b_[4] = {b4.x, b4.y, b4.z, b4.w};
      #pragma unroll
      for (int i = 0; i < 4; i++)
        #pragma unroll
        for (int j = 0; j < 4; j++)
          acc[i][j] += a_[i] * b_[j];
    }
    __syncthreads();
  }
  #pragma unroll
  for (int i = 0; i < 4; i++) {
    int row = m0 + ty * 4 + i;
    #pragma unroll
    for (int j = 0; j < 4; j++) {
      int col = tx * 4 + j;
      if (col < N) C[(size_t)row * N + col] = acc[i][j];
    }
  }
}

/* ---------------- per-head l2norm of f_q,f_k ---------------- */
__global__ __launch_bounds__(64) void l2norm_k() {
  int g = blockIdx.x;
  int lane = threadIdx.x;
  int h = g & (H_ - 1);
  int bt = g >> 4;
  size_t off = (size_t)bt * D_ + h * HD_ + lane;
  float qv = f_q[off];
  float s1 = qv * qv;
  #pragma unroll
  for (int o = 32; o > 0; o >>= 1) s1 += __shfl_xor(s1, o);
  f_q[off] = qv * rsqrtf(s1 + EPS_);
  float kv = f_k[off];
  float s2 = kv * kv;
  #pragma unroll
  for (int o = 32; o > 0; o >>= 1) s2 += __shfl_xor(s2, o);
  f_k[off] = kv * rsqrtf(s2 + EPS_);
}

/* ---------------- sigmoid(x + bias) ---------------- */
__global__ __launch_bounds__(256) void sigmoid_k(int id, float bias) {
  int i = blockIdx.x * 256 + threadIdx.x;
  float* p = fsel(id);
  float v = p[i] + bias;
  p[i] = 1.f / (1.f + expf(-v));
}

/* ================= chunked WY delta rule =================
 * prep_k: per (bh,chunk) build Tinv=(I+Ab)^-1, Gqk, KdT, row scalars.
 * chunkscan_k: per bh, sequential over chunks, all stages MFMA.      */

/* ---- prep: 1024 blocks, 256 threads ---- */
__global__ __launch_bounds__(256) void prep_k() {
  __shared__ __align__(16) unsigned short sKb[64*80];
  __shared__ __align__(16) unsigned short sQb[64*80];
  __shared__ float sAb[64*68];
  __shared__ float sX[64*68];
  __shared__ float sL[64];
  __shared__ float sB[64];
  int gid = blockIdx.x;
  int ch = gid & 31, bh = gid >> 5;
  int b = bh >> 4, h = bh & 15;
  int c0 = ch * 64;
  int tid = threadIdx.x;
  /* stage K,Q chunk -> bf16 LDS */
  {
    int row = tid >> 2, q = tid & 3;
    size_t gb = ((size_t)(b*T_ + c0 + row)) * D_ + h * HD_ + q * 16;
    const float* kg = f_k + gb;
    const float* qg = f_q + gb;
    float4 a0 = *(const float4*)(kg + 0), a1 = *(const float4*)(kg + 4);
    float4 a2 = *(const float4*)(kg + 8), a3 = *(const float4*)(kg + 12);
    *(bf16x8*)&sKb[row*80 + q*16 + 0] = cvt8(a0, a1);
    *(bf16x8*)&sKb[row*80 + q*16 + 8] = cvt8(a2, a3);
    float4 c0v = *(const float4*)(qg + 0), c1 = *(const float4*)(qg + 4);
    float4 c2 = *(const float4*)(qg + 8), c3 = *(const float4*)(qg + 12);
    *(bf16x8*)&sQb[row*80 + q*16 + 0] = cvt8(c0v, c1);
    *(bf16x8*)&sQb[row*80 + q*16 + 8] = cvt8(c2, c3);
  }
  /* log-decay inclusive scan on wave 0 */
  if (tid < 64) {
    size_t rb = ((size_t)(b*T_ + c0 + tid)) * H_ + h;
    float la = log2f(f_al[rb]);
    #pragma unroll
    for (int m = 1; m < 64; m <<= 1) {
      float o = __shfl_up(la, m);
      if (tid >= m) la += o;
    }
    sL[tid] = la;
    float bt = f_be[rb];
    sB[tid] = bt;
    float g = exp2f(la);
    g_rs[(size_t)gid*256 + tid*4 + 0] = bt;
    g_rs[(size_t)gid*256 + tid*4 + 1] = bt * g;
    g_rs[(size_t)gid*256 + tid*4 + 2] = g;
  }
  __syncthreads();
  float L63 = sL[63];
  int w = tid >> 6, lane = tid & 63, l15 = lane & 15, lg = lane >> 4;
  /* KK^T, QK^T via MFMA; wave w owns j-strip w*16 */
  bf16x8 bK[2], aK[4][2], aQ[4][2];
  #pragma unroll
  for (int k2 = 0; k2 < 2; k2++) {
    bK[k2] = *(const bf16x8*)&sKb[(w*16 + l15)*80 + k2*32 + lg*8];
    #pragma unroll
    for (int ti = 0; ti < 4; ti++) {
      aK[ti][k2] = *(const bf16x8*)&sKb[(ti*16 + l15)*80 + k2*32 + lg*8];
      aQ[ti][k2] = *(const bf16x8*)&sQb[(ti*16 + l15)*80 + k2*32 + lg*8];
    }
  }
  f32x4 ck[4] = {}, cq[4] = {};
  #pragma unroll
  for (int k2 = 0; k2 < 2; k2++)
    #pragma unroll
    for (int ti = 0; ti < 4; ti++) {
      ck[ti] = __builtin_amdgcn_mfma_f32_16x16x32_bf16(aK[ti][k2], bK[k2], ck[ti], 0, 0, 0);
      cq[ti] = __builtin_amdgcn_mfma_f32_16x16x32_bf16(aQ[ti][k2], bK[k2], cq[ti], 0, 0, 0);
    }
  /* build Ab (LDS f32) and Gqk (global bf16) */
  int j = w*16 + l15;
  float Lj = sL[j];
  #pragma unroll
  for (int ti = 0; ti < 4; ti++)
    #pragma unroll
    for (int r = 0; r < 4; r++) {
      int t = ti*16 + lg*4 + r;
      float ratio = exp2f(sL[t] - Lj);
      sAb[t*68 + j] = (j < t) ? sB[t] * ratio * ck[ti][r] : 0.f;
      float gq = (j <= t) ? ratio * cq[ti][r] : 0.f;
      g_Gqk[(size_t)gid*4096 + t*64 + j] = f2b(gq);
    }
  __syncthreads();
  /* invert (I+Ab): column-parallel substitution, 2 lanes per column */
  if (tid < 128) {
    int c = tid >> 1, p = tid & 1;
    for (int t = 0; t < 64; t++) {
      float s0 = 0.f, s1 = 0.f;
      int jj = p;
      for (; jj + 2 < t; jj += 4) {
        s0 += sAb[t*68 + jj] * sX[jj*68 + c];
        s1 += sAb[t*68 + jj + 2] * sX[(jj + 2)*68 + c];
      }
      for (; jj < t; jj += 2) s0 += sAb[t*68 + jj] * sX[jj*68 + c];
      float s = s0 + s1;
      s += __shfl_xor(s, 1);
      float xv = ((t == c) ? 1.f : 0.f) - s;
      if (p == 0) sX[t*68 + c] = xv;
    }
  }
  __syncthreads();
  /* store Tinv, KdT (bf16) */
  {
    int t = tid >> 2, q = tid & 3;
    bf16x8 o0, o1;
    #pragma unroll
    for (int i = 0; i < 8; i++) {
      o0[i] = (short)f2b(sX[t*68 + q*16 + i]);
      o1[i] = (short)f2b(sX[t*68 + q*16 + 8 + i]);
    }
    *(bf16x8*)&g_Tinv[(size_t)gid*4096 + t*64 + q*16 + 0] = o0;
    *(bf16x8*)&g_Tinv[(size_t)gid*4096 + t*64 + q*16 + 8] = o1;
    int x = t;
    bf16x8 d0, d1;
    #pragma unroll
    for (int i = 0; i < 8; i++) {
      int jj0 = q*16 + i, jj1 = q*16 + 8 + i;
      d0[i] = (short)f2b(b2f(sKb[jj0*80 + x]) * exp2f(L63 - sL[jj0]));
      d1[i] = (short)f2b(b2f(sKb[jj1*80 + x]) * exp2f(L63 - sL[jj1]));
    }
    *(bf16x8*)&g_KdT[(size_t)gid*4096 + x*64 + q*16 + 0] = d0;
    *(bf16x8*)&g_KdT[(size_t)gid*4096 + x*64 + q*16 + 8] = d1;
  }
}

/* ---- sequential chunk scan: 32 blocks (bh), 256 threads (4 waves) ---- */
__global__ __launch_bounds__(256) void chunkscan_k() {
  __shared__ float sSf[64*68];                        /* S^T f32 [y][x] */
  __shared__ __align__(16) unsigned short sSb[64*80]; /* S^T bf16 */
  __shared__ __align__(16) unsigned short sRb[64*80]; /* RHS^T bf16 [y][j] */
  __shared__ __align__(16) unsigned short sUb[64*80]; /* U^T bf16 [y][j] */
  int bh = blockIdx.x;
  int b = bh >> 4, h = bh & 15;
  int tid = threadIdx.x, w = tid >> 6, lane = tid & 63;
  int l15 = lane & 15, lg = lane >> 4;
  for (int i = tid; i < 64*68; i += 256) sSf[i] = 0.f;
  for (int i = tid; i < 64*80; i += 256) sSb[i] = 0;
  __syncthreads();
  int tcol = w*16 + l15;               /* this wave's N-strip index */
  for (int ch = 0; ch < NCH_; ch++) {
    size_t gid = (size_t)bh * NCH_ + ch;
    int c0 = ch * 64;
    size_t grow = ((size_t)(b*T_ + c0 + tcol)) * D_ + h * HD_;
    /* scalars */
    float s1 = g_rs[gid*256 + tcol*4 + 0];
    float s2 = g_rs[gid*256 + tcol*4 + 1];
    float gam = g_rs[gid*256 + tcol*4 + 2];
    float gC = g_rs[gid*256 + 63*4 + 2];
    /* B-fragments: Kc,Qc (f32->bf16), Tinv,Gqk,KdT (bf16) */
    bf16x8 bKc[2], bQc[2], bTi[2], bGq[2], bKd[2];
    #pragma unroll
    for (int k2 = 0; k2 < 2; k2++) {
      const float* kp = f_k + grow + k2*32 + lg*8;
      const float* qp = f_q + grow + k2*32 + lg*8;
      bKc[k2] = cvt8(*(const float4*)(kp), *(const float4*)(kp + 4));
      bQc[k2] = cvt8(*(const float4*)(qp), *(const float4*)(qp + 4));
      bTi[k2] = *(const bf16x8*)&g_Tinv[gid*4096 + tcol*64 + k2*32 + lg*8];
      bGq[k2] = *(const bf16x8*)&g_Gqk[gid*4096 + tcol*64 + k2*32 + lg*8];
      bKd[k2] = *(const bf16x8*)&g_KdT[gid*4096 + tcol*64 + k2*32 + lg*8];
    }
    /* v values at (t=tcol, y=ti*16+lg*4+r) */
    float vr[4][4];
    #pragma unroll
    for (int ti = 0; ti < 4; ti++)
      #pragma unroll
      for (int r = 0; r < 4; r++)
        vr[ti][r] = f_v[grow + ti*16 + lg*4 + r];
    /* phase 1: KST = S^T @ Kc^T ; RHS^T = s1*v - s2*KST */
    f32x4 acc[4] = {};
    #pragma unroll
    for (int k2 = 0; k2 < 2; k2++)
      #pragma unroll
      for (int ti = 0; ti < 4; ti++) {
        bf16x8 aS = *(const bf16x8*)&sSb[(ti*16 + l15)*80 + k2*32 + lg*8];
        acc[ti] = __builtin_amdgcn_mfma_f32_16x16x32_bf16(aS, bKc[k2], acc[ti], 0, 0, 0);
      }
    #pragma unroll
    for (int ti = 0; ti < 4; ti++)
      #pragma unroll
      for (int r = 0; r < 4; r++)
        sRb[(ti*16 + lg*4 + r)*80 + tcol] = f2b(s1 * vr[ti][r] - s2 * acc[ti][r]);
    __syncthreads();
    /* phase 2: U^T = RHS^T @ Tinv^T */
    f32x4 uac[4] = {};
    #pragma unroll
    for (int k2 = 0; k2 < 2; k2++)
      #pragma unroll
      for (int ti = 0; ti < 4; ti++) {
        bf16x8 aR = *(const bf16x8*)&sRb[(ti*16 + l15)*80 + k2*32 + lg*8];
        uac[ti] = __builtin_amdgcn_mfma_f32_16x16x32_bf16(aR, bTi[k2], uac[ti], 0, 0, 0);
      }
    #pragma unroll
    for (int ti = 0; ti < 4; ti++)
      #pragma unroll
      for (int r = 0; r < 4; r++)
        sUb[(ti*16 + lg*4 + r)*80 + tcol] = f2b(uac[ti][r]);
    __syncthreads();
    /* phase 3: O^T = gam*(S^T@Qc^T) + U^T@Gqk^T ; write b_o */
    f32x4 oac[4] = {};
    #pragma unroll
    for (int k2 = 0; k2 < 2; k2++)
      #pragma unroll
      for (int ti = 0; ti < 4; ti++) {
        bf16x8 aS = *(const bf16x8*)&sSb[(ti*16 + l15)*80 + k2*32 + lg*8];
        oac[ti] = __builtin_amdgcn_mfma_f32_16x16x32_bf16(aS, bQc[k2], oac[ti], 0, 0, 0);
      }
    #pragma unroll
    for (int ti = 0; ti < 4; ti++)
      #pragma unroll
      for (int r = 0; r < 4; r++)
        oac[ti][r] *= gam;
    #pragma unroll
    for (int k2 = 0; k2 < 2; k2++)
      #pragma unroll
      for (int ti = 0; ti < 4; ti++) {
        bf16x8 aU = *(const bf16x8*)&sUb[(ti*16 + l15)*80 + k2*32 + lg*8];
        oac[ti] = __builtin_amdgcn_mfma_f32_16x16x32_bf16(aU, bGq[k2], oac[ti], 0, 0, 0);
      }
    #pragma unroll
    for (int ti = 0; ti < 4; ti++)
      #pragma unroll
      for (int r = 0; r < 4; r++)
        b_o[grow + ti*16 + lg*4 + r] = f2b(oac[ti][r]);
    __syncthreads();
    /* phase 4: S^T' = gC*S^T + U^T@KdT^T */
    f32x4 sac[4];
    #pragma unroll
    for (int ti = 0; ti < 4; ti++)
      #pragma unroll
      for (int r = 0; r < 4; r++)
        sac[ti][r] = gC * sSf[(ti*16 + lg*4 + r)*68 + tcol];
    #pragma unroll
    for (int k2 = 0; k2 < 2; k2++)
      #pragma unroll
      for (int ti = 0; ti < 4; ti++) {
        bf16x8 aU = *(const bf16x8*)&sUb[(ti*16 + l15)*80 + k2*32 + lg*8];
        sac[ti] = __builtin_amdgcn_mfma_f32_16x16x32_bf16(aU, bKd[k2], sac[ti], 0, 0, 0);
      }
    #pragma unroll
    for (int ti = 0; ti < 4; ti++)
      #pragma unroll
      for (int r = 0; r < 4; r++) {
        int y = ti*16 + lg*4 + r;
        sSf[y*68 + tcol] = sac[ti][r];
        sSb[y*80 + tcol] = f2b(sac[ti][r]);
      }
    __syncthreads();
  }
}

/* ---------------- elementwise ---------------- */
__global__ __launch_bounds__(256) void add_h_k(const float* __restrict__ x) {
  int i = blockIdx.x * 256 + threadIdx.x;
  f_h[i] = x[i] + f_mix[i];
}
__global__ __launch_bounds__(256) void add_out_k(float* __restrict__ o) {
  int i = blockIdx.x * 256 + threadIdx.x;
  o[i] = f_h[i] + f_ffn[i];
}
__global__ __launch_bounds__(256) void swiglu2_k() {
  int col = blockIdx.x * 256 + threadIdx.x;
  size_t i = (size_t)blockIdx.y * IP_ + col;
  float x = f_g[i];
  float s = x / (1.f + expf(-x));
  b_f[i] = f2b(s * f_u[i]);
}

extern "C" void kernel_launch(void* const* d_in, const int* in_sizes, int n_in,
                              void* d_out, int out_size, void* d_ws, size_t ws_size,
                              hipStream_t stream) {
  const float* x   = (const float*)d_in[0];
  const float* n1w = (const float*)d_in[1];
  const float* n2w = (const float*)d_in[2];
  const float* cw  = (const float*)d_in[3];
  const float* cb  = (const float*)d_in[4];
  const float* wq  = (const float*)d_in[5];
  const float* wk  = (const float*)d_in[6];
  const float* wv  = (const float*)d_in[7];
  const float* wb  = (const float*)d_in[8];
  const float* wa  = (const float*)d_in[9];
  const float* wo  = (const float*)d_in[10];
  const float* wg  = (const float*)d_in[11];
  const float* wu  = (const float*)d_in[12];
  const float* wd  = (const float*)d_in[13];
  float* out = (float*)d_out;

  castT_k<<<dim3(16, 16), 256, 0, stream>>>(wq, D_, D_, 4, D_, D_);
  castT_k<<<dim3(16, 16), 256, 0, stream>>>(wk, D_, D_, 5, D_, D_);
  castT_k<<<dim3(16, 16), 256, 0, stream>>>(wv, D_, D_, 6, D_, D_);
  castT_k<<<dim3(16, 16), 256, 0, stream>>>(wo, D_, D_, 7, D_, D_);
  castT_k<<<dim3(44, 16), 256, 0, stream>>>(wg, D_, I_, 8, D_, IP_);
  castT_k<<<dim3(44, 16), 256, 0, stream>>>(wu, D_, I_, 9, D_, IP_);
  castT_k<<<dim3(16, 44), 256, 0, stream>>>(wd, I_, D_, 10, IP_, D_);

  rms1_k<<<BT_, 256, 0, stream>>>(x, n1w);
  conv2_k<<<ND_ / 256, 256, 0, stream>>>(cw, cb);

  gemm_bf16<<<dim3(8, 32), 256, 0, stream>>>(0, 4, 0, D_, D_);   /* q */
  gemm_bf16<<<dim3(8, 32), 256, 0, stream>>>(0, 5, 1, D_, D_);   /* k */
  gemm_bf16<<<dim3(8, 32), 256, 0, stream>>>(0, 6, 2, D_, D_);   /* v */
  gemmba_k<<<dim3(1, 64), 256, 0, stream>>>(wb, 3);              /* beta  */
  gemmba_k<<<dim3(1, 64), 256, 0, stream>>>(wa, 4);              /* alpha */

  l2norm_k<<<NH_, 64, 0, stream>>>();
  sigmoid_k<<<NH_ / 256, 256, 0, stream>>>(3, 0.f);
  sigmoid_k<<<NH_ / 256, 256, 0, stream>>>(4, GATE_BIAS_);

  prep_k<<<NG_, 256, 0, stream>>>();
  chunkscan_k<<<32, 256, 0, stream>>>();

  gemm_bf16<<<dim3(8, 32), 256, 0, stream>>>(1, 7, 5, D_, D_);   /* mix */
  add_h_k<<<ND_ / 256, 256, 0, stream>>>(x);
  rms2_k<<<BT_, 256, 0, stream>>>(n2w);
  gemm_bf16<<<dim3(22, 32), 256, 0, stream>>>(2, 8, 6, D_, IP_);
  gemm_bf16<<<dim3(22, 32), 256, 0, stream>>>(2, 9, 7, D_, IP_);
  swiglu2_k<<<dim3(IP_ / 256, BT_), 256, 0, stream>>>();
  gemm_bf16<<<dim3(8, 32), 256, 0, stream>>>(3, 10, 8, IP_, D_);
  add_out_k<<<ND_ / 256, 256, 0, stream>>>(out);
}

// Round 6
// 616.498 us; speedup vs baseline: 5.1686x; 1.5322x over previous
//
#include <hip/hip_runtime.h>
#include <math.h>

#define D_ 1024
#define H_ 16
#define HD_ 64
#define KW_ 4
#define I_ 2764
#define IP_ 2816              /* I padded to 22*128 */
#define NQKV_ 3200            /* q|k|v|gates fused N, 25*128 */
#define NGU_ 5632             /* interleaved g/u N, 44*128 */
#define B_ 2
#define T_ 2048
#define BT_ (B_*T_)           /* 4096 */
#define ND_ (BT_*D_)          /* 4194304 */
#define NH_ (BT_*H_)          /* 65536 */
#define NCH_ 32               /* chunks per sequence (T/64) */
#define NG_ (32*NCH_)         /* 1024 (bh,chunk) groups */
#define EPS_ 1e-6f
#define GATE_BIAS_ 4.0f

typedef __attribute__((ext_vector_type(8))) short bf16x8;
typedef __attribute__((ext_vector_type(4))) float f32x4;

/* ---------------- static buffers ---------------- */
__device__ float f_sc1[BT_];
__device__ float f_q[ND_];
__device__ float f_k[ND_];
__device__ float f_v[ND_];
__device__ float f_be[NH_];
__device__ float f_al[NH_];
__device__ float f_h[ND_];
__device__ float g_rs[NG_ * 256];
__device__ unsigned short g_Tinv[(size_t)NG_*4096];
__device__ unsigned short g_Gqk[(size_t)NG_*4096];
__device__ unsigned short g_KdT[(size_t)NG_*4096];
__device__ unsigned short b_xc[ND_];
__device__ unsigned short b_o[ND_];
__device__ unsigned short b_hn[ND_];
__device__ unsigned short b_f[(size_t)BT_*IP_];
__device__ unsigned short b_wqkvT[(size_t)NQKV_*D_];
__device__ unsigned short b_woT[D_*D_];
__device__ unsigned short b_wguT[(size_t)NGU_*D_];
__device__ unsigned short b_wdT[(size_t)D_*IP_];

__device__ __forceinline__ unsigned short f2b(float x) {
  union { float f; unsigned u; } a; a.f = x;
  unsigned r = a.u + 0x7fff + ((a.u >> 16) & 1);
  return (unsigned short)(r >> 16);
}
__device__ __forceinline__ float b2f(unsigned short s) {
  union { unsigned u; float f; } a; a.u = ((unsigned)s) << 16; return a.f;
}
__device__ __forceinline__ bf16x8 cvt8(float4 a, float4 b) {
  bf16x8 r;
  r[0] = (short)f2b(a.x); r[1] = (short)f2b(a.y);
  r[2] = (short)f2b(a.z); r[3] = (short)f2b(a.w);
  r[4] = (short)f2b(b.x); r[5] = (short)f2b(b.y);
  r[6] = (short)f2b(b.z); r[7] = (short)f2b(b.w);
  return r;
}

__device__ __forceinline__ const unsigned short* bsel(int id) {
  switch (id) {
    case 0: return b_xc;  case 1: return b_o;    case 2: return b_hn;
    case 3: return b_f;   case 4: return b_wqkvT; case 5: return b_woT;
    case 6: return b_wguT; default: return b_wdT;
  }
}
__device__ __forceinline__ unsigned short* bselw(int id) {
  return (unsigned short*)bsel(id);
}

/* ---------------- RMSNorm-1 scale only: f_sc1[row] ---------------- */
__global__ __launch_bounds__(256) void rmssc_k(const float* __restrict__ x) {
  int row = blockIdx.x;
  int tid = threadIdx.x;
  float4 v = ((const float4*)(x + (size_t)row * D_))[tid];
  float ss = v.x*v.x + v.y*v.y + v.z*v.z + v.w*v.w;
  #pragma unroll
  for (int o = 32; o > 0; o >>= 1) ss += __shfl_down(ss, o);
  __shared__ float sred[4];
  if ((tid & 63) == 0) sred[tid >> 6] = ss;
  __syncthreads();
  if (tid == 0)
    f_sc1[row] = rsqrtf((sred[0]+sred[1]+sred[2]+sred[3]) / (float)D_ + EPS_);
}

/* ---------------- RMSNorm 2 -> bf16 b_hn ---------------- */
__global__ __launch_bounds__(256) void rms2_k(const float* __restrict__ w) {
  int row = blockIdx.x;
  const float* xr = f_h + (size_t)row * D_;
  int tid = threadIdx.x;
  float4 v = ((const float4*)xr)[tid];
  float ss = v.x*v.x + v.y*v.y + v.z*v.z + v.w*v.w;
  #pragma unroll
  for (int o = 32; o > 0; o >>= 1) ss += __shfl_down(ss, o);
  __shared__ float sred[4];
  __shared__ float sscale;
  if ((tid & 63) == 0) sred[tid >> 6] = ss;
  __syncthreads();
  if (tid == 0)
    sscale = rsqrtf((sred[0]+sred[1]+sred[2]+sred[3]) / (float)D_ + EPS_);
  __syncthreads();
  float s = sscale;
  float4 wv = ((const float4*)w)[tid];
  unsigned short* orow = b_hn + (size_t)row * D_ + tid * 4;
  orow[0] = f2b(v.x*s*wv.x); orow[1] = f2b(v.y*s*wv.y);
  orow[2] = f2b(v.z*s*wv.z); orow[3] = f2b(v.w*s*wv.w);
}

/* ---------------- causal depthwise conv + inline rmsnorm + SiLU -> b_xc ---------------- */
__global__ __launch_bounds__(256) void conv2_k(const float* __restrict__ x,
                                               const float* __restrict__ cw,
                                               const float* __restrict__ cb,
                                               const float* __restrict__ n1w) {
  int idx = blockIdx.x * 256 + threadIdx.x;
  int d = idx & (D_ - 1);
  int bt = idx >> 10;
  int t = bt & (T_ - 1);
  float wd = n1w[d];
  float acc = cb[d];
  #pragma unroll
  for (int j = 0; j < KW_; j++) {
    int tt = t - (KW_ - 1) + j;
    if (tt >= 0) {
      int off = j - (KW_ - 1);
      acc += x[(size_t)idx + (size_t)off * D_] * f_sc1[bt + off] * wd * cw[d * KW_ + j];
    }
  }
  float s = acc / (1.f + expf(-acc));
  b_xc[idx] = f2b(s);
}

/* ---------------- fused QKV+gates weight cast+transpose -> b_wqkvT[3200][1024] ---------------- */
__global__ __launch_bounds__(256) void castTqkv_k(const float* __restrict__ wq,
                                                  const float* __restrict__ wk,
                                                  const float* __restrict__ wv,
                                                  const float* __restrict__ wb,
                                                  const float* __restrict__ wa) {
  __shared__ float s[64][65];
  int n0 = blockIdx.x * 64, k0 = blockIdx.y * 64;
  int tx = threadIdx.x & 63, ty = threadIdx.x >> 6;
  int nn = n0 + tx;
  const float* src = nullptr; int col = 0, ld = 1024;
  if (nn < 1024)      { src = wq; col = nn; }
  else if (nn < 2048) { src = wk; col = nn - 1024; }
  else if (nn < 3072) { src = wv; col = nn - 2048; }
  else if (nn < 3088) { src = wb; col = nn - 3072; ld = 16; }
  else if (nn < 3104) { src = wa; col = nn - 3088; ld = 16; }
  #pragma unroll
  for (int j = ty; j < 64; j += 4)
    s[j][tx] = src ? src[(size_t)(k0 + j) * ld + col] : 0.f;
  __syncthreads();
  #pragma unroll
  for (int j = ty; j < 64; j += 4)
    b_wqkvT[(size_t)(n0 + j) * D_ + k0 + tx] = f2b(s[tx][j]);
}

/* ---------------- interleaved G/U weight cast -> b_wguT[5632][1024] ----------------
 * fused row c: k16=c>>5, inner=c&31; inner<16 -> wg col k16*16+inner, else wu. */
__global__ __launch_bounds__(256) void castTgu_k(const float* __restrict__ wg,
                                                 const float* __restrict__ wu) {
  __shared__ float s[64][65];
  int n0 = blockIdx.x * 64, k0 = blockIdx.y * 64;
  int tx = threadIdx.x & 63, ty = threadIdx.x >> 6;
  int nn = n0 + tx;
  int inner = nn & 31;
  int col = (nn >> 5) * 16 + (inner & 15);
  const float* src = (inner < 16) ? wg : wu;
  bool ok = (col < I_);
  #pragma unroll
  for (int j = ty; j < 64; j += 4)
    s[j][tx] = ok ? src[(size_t)(k0 + j) * I_ + col] : 0.f;
  __syncthreads();
  #pragma unroll
  for (int j = ty; j < 64; j += 4)
    b_wguT[(size_t)(n0 + j) * D_ + k0 + tx] = f2b(s[tx][j]);
}

/* ---------------- plain weight cast+transpose ---------------- */
__global__ __launch_bounds__(256) void castT_k(const float* __restrict__ W,
                                               int K, int N, int outid, int Kp) {
  __shared__ float s[64][65];
  unsigned short* out = bselw(outid);
  int k0 = blockIdx.y * 64, n0 = blockIdx.x * 64;
  int tx = threadIdx.x & 63, ty = threadIdx.x >> 6;
  #pragma unroll
  for (int j = ty; j < 64; j += 4) {
    int kk = k0 + j, nn = n0 + tx;
    s[j][tx] = (kk < K && nn < N) ? W[(size_t)kk * N + nn] : 0.f;
  }
  __syncthreads();
  #pragma unroll
  for (int j = ty; j < 64; j += 4)
    out[(size_t)(n0 + j) * Kp + k0 + tx] = f2b(s[tx][j]);
}

/* ---------------- bf16 MFMA GEMM (128x128 tile, BK=32), fused epilogues ----------------
 * mode 0: QKV -> f_q/f_k (l2-normalized), f_v, f_be/f_al (sigmoid)
 * mode 1: GU  -> b_f = bf16(silu(g)*u), interleaved cols
 * mode 2: f_h = ext + acc
 * mode 3: eout = f_h + acc                                                  */
__global__ __launch_bounds__(256) void gemm_bf16(int aid, int bid, int Kp, int mode,
                                                 const float* __restrict__ ext,
                                                 float* __restrict__ eout) {
  __shared__ __align__(16) unsigned short Al[128 * 32];
  __shared__ __align__(16) unsigned short Bl[128 * 32];
  const unsigned short* A = bsel(aid);
  const unsigned short* Bt = bsel(bid);
  int tid = threadIdx.x;
  int m0 = blockIdx.y * 128, n0 = blockIdx.x * 128;
  int wave = tid >> 6, lane = tid & 63;
  int wm = (wave >> 1) * 64, wn = (wave & 1) * 64;
  int lrow = tid >> 2;
  int lcol = (tid & 3) * 8;
  f32x4 acc[4][4] = {};
  const int l15 = lane & 15, lg = lane >> 4;
  for (int k0 = 0; k0 < Kp; k0 += 32) {
    const unsigned short* Ag = A + (size_t)m0 * Kp + k0;
    const unsigned short* Bg = Bt + (size_t)n0 * Kp + k0;
    __builtin_amdgcn_global_load_lds(
      (const __attribute__((address_space(1))) void*)(Ag + (size_t)lrow * Kp + lcol),
      (__attribute__((address_space(3))) void*)(Al + wave * 512), 16, 0, 0);
    __builtin_amdgcn_global_load_lds(
      (const __attribute__((address_space(1))) void*)(Ag + (size_t)(64 + lrow) * Kp + lcol),
      (__attribute__((address_space(3))) void*)(Al + 2048 + wave * 512), 16, 0, 0);
    __builtin_amdgcn_global_load_lds(
      (const __attribute__((address_space(1))) void*)(Bg + (size_t)lrow * Kp + lcol),
      (__attribute__((address_space(3))) void*)(Bl + wave * 512), 16, 0, 0);
    __builtin_amdgcn_global_load_lds(
      (const __attribute__((address_space(1))) void*)(Bg + (size_t)(64 + lrow) * Kp + lcol),
      (__attribute__((address_space(3))) void*)(Bl + 2048 + wave * 512), 16, 0, 0);
    __syncthreads();
    bf16x8 af[4], bf[4];
    #pragma unroll
    for (int i = 0; i < 4; i++)
      af[i] = *(const bf16x8*)&Al[(wm + i * 16 + l15) * 32 + lg * 8];
    #pragma unroll
    for (int j = 0; j < 4; j++)
      bf[j] = *(const bf16x8*)&Bl[(wn + j * 16 + l15) * 32 + lg * 8];
    #pragma unroll
    for (int i = 0; i < 4; i++)
      #pragma unroll
      for (int j = 0; j < 4; j++)
        acc[i][j] = __builtin_amdgcn_mfma_f32_16x16x32_bf16(af[i], bf[j], acc[i][j], 0, 0, 0);
    __syncthreads();
  }
  int C0 = n0 + wn;
  if (mode == 0) {
    if (C0 < 2048) {                     /* q or k: per-head l2norm */
      float* dst = (C0 < 1024) ? f_q : f_k;
      int cbase = C0 & 1023;
      #pragma unroll
      for (int i = 0; i < 4; i++) {
        int r0i = m0 + wm + i * 16 + lg * 4;
        #pragma unroll
        for (int r = 0; r < 4; r++) {
          float ss = acc[i][0][r]*acc[i][0][r] + acc[i][1][r]*acc[i][1][r]
                   + acc[i][2][r]*acc[i][2][r] + acc[i][3][r]*acc[i][3][r];
          ss += __shfl_xor(ss, 1); ss += __shfl_xor(ss, 2);
          ss += __shfl_xor(ss, 4); ss += __shfl_xor(ss, 8);
          float sc = rsqrtf(ss + EPS_);
          #pragma unroll
          for (int j = 0; j < 4; j++)
            dst[(size_t)(r0i + r) * D_ + cbase + j * 16 + l15] = acc[i][j][r] * sc;
        }
      }
    } else if (C0 < 3072) {              /* v plain */
      int cbase = C0 & 1023;
      #pragma unroll
      for (int i = 0; i < 4; i++) {
        int r0i = m0 + wm + i * 16 + lg * 4;
        #pragma unroll
        for (int j = 0; j < 4; j++)
          #pragma unroll
          for (int r = 0; r < 4; r++)
            f_v[(size_t)(r0i + r) * D_ + cbase + j * 16 + l15] = acc[i][j][r];
      }
    } else if (C0 == 3072) {             /* beta (j=0) / alpha (j=1) */
      #pragma unroll
      for (int i = 0; i < 4; i++) {
        int r0i = m0 + wm + i * 16 + lg * 4;
        #pragma unroll
        for (int r = 0; r < 4; r++) {
          float vb = acc[i][0][r];
          f_be[(size_t)(r0i + r) * H_ + l15] = 1.f / (1.f + expf(-vb));
          float va = acc[i][1][r] + GATE_BIAS_;
          f_al[(size_t)(r0i + r) * H_ + l15] = 1.f / (1.f + expf(-va));
        }
      }
    }
  } else if (mode == 1) {                /* swiglu -> b_f */
    #pragma unroll
    for (int i = 0; i < 4; i++) {
      int r0i = m0 + wm + i * 16 + lg * 4;
      #pragma unroll
      for (int jp = 0; jp < 2; jp++) {
        int j = jp * 2;
        int Lbase = ((C0 + j * 16) >> 5) * 16;
        #pragma unroll
        for (int r = 0; r < 4; r++) {
          float g = acc[i][j][r], u = acc[i][j + 1][r];
          float sg = g / (1.f + expf(-g));
          b_f[(size_t)(r0i + r) * IP_ + Lbase + l15] = f2b(sg * u);
        }
      }
    }
  } else if (mode == 2) {                /* f_h = ext + acc */
    #pragma unroll
    for (int i = 0; i < 4; i++) {
      int r0i = m0 + wm + i * 16 + lg * 4;
      #pragma unroll
      for (int j = 0; j < 4; j++)
        #pragma unroll
        for (int r = 0; r < 4; r++) {
          size_t off = (size_t)(r0i + r) * D_ + C0 + j * 16 + l15;
          f_h[off] = ext[off] + acc[i][j][r];
        }
    }
  } else {                               /* eout = f_h + acc */
    #pragma unroll
    for (int i = 0; i < 4; i++) {
      int r0i = m0 + wm + i * 16 + lg * 4;
      #pragma unroll
      for (int j = 0; j < 4; j++)
        #pragma unroll
        for (int r = 0; r < 4; r++) {
          size_t off = (size_t)(r0i + r) * D_ + C0 + j * 16 + l15;
          eout[off] = f_h[off] + acc[i][j][r];
        }
    }
  }
}

/* ================= chunked WY delta rule ================= */
__global__ __launch_bounds__(256) void prep_k() {
  __shared__ __align__(16) unsigned short sKb[64*80];
  __shared__ __align__(16) unsigned short sQb[64*80];
  __shared__ float sAb[64*68];
  __shared__ float sX[64*68];
  __shared__ float sL[64];
  __shared__ float sB[64];
  int gid = blockIdx.x;
  int ch = gid & 31, bh = gid >> 5;
  int b = bh >> 4, h = bh & 15;
  int c0 = ch * 64;
  int tid = threadIdx.x;
  {
    int row = tid >> 2, q = tid & 3;
    size_t gb = ((size_t)(b*T_ + c0 + row)) * D_ + h * HD_ + q * 16;
    const float* kg = f_k + gb;
    const float* qg = f_q + gb;
    float4 a0 = *(const float4*)(kg + 0), a1 = *(const float4*)(kg + 4);
    float4 a2 = *(const float4*)(kg + 8), a3 = *(const float4*)(kg + 12);
    *(bf16x8*)&sKb[row*80 + q*16 + 0] = cvt8(a0, a1);
    *(bf16x8*)&sKb[row*80 + q*16 + 8] = cvt8(a2, a3);
    float4 c0v = *(const float4*)(qg + 0), c1 = *(const float4*)(qg + 4);
    float4 c2 = *(const float4*)(qg + 8), c3 = *(const float4*)(qg + 12);
    *(bf16x8*)&sQb[row*80 + q*16 + 0] = cvt8(c0v, c1);
    *(bf16x8*)&sQb[row*80 + q*16 + 8] = cvt8(c2, c3);
  }
  if (tid < 64) {
    size_t rb = ((size_t)(b*T_ + c0 + tid)) * H_ + h;
    float la = log2f(f_al[rb]);
    #pragma unroll
    for (int m = 1; m < 64; m <<= 1) {
      float o = __shfl_up(la, m);
      if (tid >= m) la += o;
    }
    sL[tid] = la;
    float bt = f_be[rb];
    sB[tid] = bt;
    float g = exp2f(la);
    g_rs[(size_t)gid*256 + tid*4 + 0] = bt;
    g_rs[(size_t)gid*256 + tid*4 + 1] = bt * g;
    g_rs[(size_t)gid*256 + tid*4 + 2] = g;
  }
  __syncthreads();
  float L63 = sL[63];
  int w = tid >> 6, lane = tid & 63, l15 = lane & 15, lg = lane >> 4;
  bf16x8 bK[2], aK[4][2], aQ[4][2];
  #pragma unroll
  for (int k2 = 0; k2 < 2; k2++) {
    bK[k2] = *(const bf16x8*)&sKb[(w*16 + l15)*80 + k2*32 + lg*8];
    #pragma unroll
    for (int ti = 0; ti < 4; ti++) {
      aK[ti][k2] = *(const bf16x8*)&sKb[(ti*16 + l15)*80 + k2*32 + lg*8];
      aQ[ti][k2] = *(const bf16x8*)&sQb[(ti*16 + l15)*80 + k2*32 + lg*8];
    }
  }
  f32x4 ck[4] = {}, cq[4] = {};
  #pragma unroll
  for (int k2 = 0; k2 < 2; k2++)
    #pragma unroll
    for (int ti = 0; ti < 4; ti++) {
      ck[ti] = __builtin_amdgcn_mfma_f32_16x16x32_bf16(aK[ti][k2], bK[k2], ck[ti], 0, 0, 0);
      cq[ti] = __builtin_amdgcn_mfma_f32_16x16x32_bf16(aQ[ti][k2], bK[k2], cq[ti], 0, 0, 0);
    }
  int j = w*16 + l15;
  float Lj = sL[j];
  #pragma unroll
  for (int ti = 0; ti < 4; ti++)
    #pragma unroll
    for (int r = 0; r < 4; r++) {
      int t = ti*16 + lg*4 + r;
      float ratio = exp2f(sL[t] - Lj);
      sAb[t*68 + j] = (j < t) ? sB[t] * ratio * ck[ti][r] : 0.f;
      float gq = (j <= t) ? ratio * cq[ti][r] : 0.f;
      g_Gqk[(size_t)gid*4096 + t*64 + j] = f2b(gq);
    }
  __syncthreads();
  if (tid < 128) {
    int c = tid >> 1, p = tid & 1;
    for (int t = 0; t < 64; t++) {
      float s0 = 0.f, s1 = 0.f;
      int jj = p;
      for (; jj + 2 < t; jj += 4) {
        s0 += sAb[t*68 + jj] * sX[jj*68 + c];
        s1 += sAb[t*68 + jj + 2] * sX[(jj + 2)*68 + c];
      }
      for (; jj < t; jj += 2) s0 += sAb[t*68 + jj] * sX[jj*68 + c];
      float s = s0 + s1;
      s += __shfl_xor(s, 1);
      float xv = ((t == c) ? 1.f : 0.f) - s;
      if (p == 0) sX[t*68 + c] = xv;
    }
  }
  __syncthreads();
  {
    int t = tid >> 2, q = tid & 3;
    bf16x8 o0, o1;
    #pragma unroll
    for (int i = 0; i < 8; i++) {
      o0[i] = (short)f2b(sX[t*68 + q*16 + i]);
      o1[i] = (short)f2b(sX[t*68 + q*16 + 8 + i]);
    }
    *(bf16x8*)&g_Tinv[(size_t)gid*4096 + t*64 + q*16 + 0] = o0;
    *(bf16x8*)&g_Tinv[(size_t)gid*4096 + t*64 + q*16 + 8] = o1;
    int x = t;
    bf16x8 d0, d1;
    #pragma unroll
    for (int i = 0; i < 8; i++) {
      int jj0 = q*16 + i, jj1 = q*16 + 8 + i;
      d0[i] = (short)f2b(b2f(sKb[jj0*80 + x]) * exp2f(L63 - sL[jj0]));
      d1[i] = (short)f2b(b2f(sKb[jj1*80 + x]) * exp2f(L63 - sL[jj1]));
    }
    *(bf16x8*)&g_KdT[(size_t)gid*4096 + x*64 + q*16 + 0] = d0;
    *(bf16x8*)&g_KdT[(size_t)gid*4096 + x*64 + q*16 + 8] = d1;
  }
}

__global__ __launch_bounds__(256) void chunkscan_k() {
  __shared__ float sSf[64*68];
  __shared__ __align__(16) unsigned short sSb[64*80];
  __shared__ __align__(16) unsigned short sRb[64*80];
  __shared__ __align__(16) unsigned short sUb[64*80];
  int bh = blockIdx.x;
  int b = bh >> 4, h = bh & 15;
  int tid = threadIdx.x, w = tid >> 6, lane = tid & 63;
  int l15 = lane & 15, lg = lane >> 4;
  for (int i = tid; i < 64*68; i += 256) sSf[i] = 0.f;
  for (int i = tid; i < 64*80; i += 256) sSb[i] = 0;
  __syncthreads();
  int tcol = w*16 + l15;
  for (int ch = 0; ch < NCH_; ch++) {
    size_t gid = (size_t)bh * NCH_ + ch;
    int c0 = ch * 64;
    size_t grow = ((size_t)(b*T_ + c0 + tcol)) * D_ + h * HD_;
    float s1 = g_rs[gid*256 + tcol*4 + 0];
    float s2 = g_rs[gid*256 + tcol*4 + 1];
    float gam = g_rs[gid*256 + tcol*4 + 2];
    float gC = g_rs[gid*256 + 63*4 + 2];
    bf16x8 bKc[2], bQc[2], bTi[2], bGq[2], bKd[2];
    #pragma unroll
    for (int k2 = 0; k2 < 2; k2++) {
      const float* kp = f_k + grow + k2*32 + lg*8;
      const float* qp = f_q + grow + k2*32 + lg*8;
      bKc[k2] = cvt8(*(const float4*)(kp), *(const float4*)(kp + 4));
      bQc[k2] = cvt8(*(const float4*)(qp), *(const float4*)(qp + 4));
      bTi[k2] = *(const bf16x8*)&g_Tinv[gid*4096 + tcol*64 + k2*32 + lg*8];
      bGq[k2] = *(const bf16x8*)&g_Gqk[gid*4096 + tcol*64 + k2*32 + lg*8];
      bKd[k2] = *(const bf16x8*)&g_KdT[gid*4096 + tcol*64 + k2*32 + lg*8];
    }
    float vr[4][4];
    #pragma unroll
    for (int ti = 0; ti < 4; ti++)
      #pragma unroll
      for (int r = 0; r < 4; r++)
        vr[ti][r] = f_v[grow + ti*16 + lg*4 + r];
    f32x4 acc[4] = {};
    #pragma unroll
    for (int k2 = 0; k2 < 2; k2++)
      #pragma unroll
      for (int ti = 0; ti < 4; ti++) {
        bf16x8 aS = *(const bf16x8*)&sSb[(ti*16 + l15)*80 + k2*32 + lg*8];
        acc[ti] = __builtin_amdgcn_mfma_f32_16x16x32_bf16(aS, bKc[k2], acc[ti], 0, 0, 0);
      }
    #pragma unroll
    for (int ti = 0; ti < 4; ti++)
      #pragma unroll
      for (int r = 0; r < 4; r++)
        sRb[(ti*16 + lg*4 + r)*80 + tcol] = f2b(s1 * vr[ti][r] - s2 * acc[ti][r]);
    __syncthreads();
    f32x4 uac[4] = {};
    #pragma unroll
    for (int k2 = 0; k2 < 2; k2++)
      #pragma unroll
      for (int ti = 0; ti < 4; ti++) {
        bf16x8 aR = *(const bf16x8*)&sRb[(ti*16 + l15)*80 + k2*32 + lg*8];
        uac[ti] = __builtin_amdgcn_mfma_f32_16x16x32_bf16(aR, bTi[k2], uac[ti], 0, 0, 0);
      }
    #pragma unroll
    for (int ti = 0; ti < 4; ti++)
      #pragma unroll
      for (int r = 0; r < 4; r++)
        sUb[(ti*16 + lg*4 + r)*80 + tcol] = f2b(uac[ti][r]);
    __syncthreads();
    f32x4 oac[4] = {};
    #pragma unroll
    for (int k2 = 0; k2 < 2; k2++)
      #pragma unroll
      for (int ti = 0; ti < 4; ti++) {
        bf16x8 aS = *(const bf16x8*)&sSb[(ti*16 + l15)*80 + k2*32 + lg*8];
        oac[ti] = __builtin_amdgcn_mfma_f32_16x16x32_bf16(aS, bQc[k2], oac[ti], 0, 0, 0);
      }
    #pragma unroll
    for (int ti = 0; ti < 4; ti++)
      #pragma unroll
      for (int r = 0; r < 4; r++)
        oac[ti][r] *= gam;
    #pragma unroll
    for (int k2 = 0; k2 < 2; k2++)
      #pragma unroll
      for (int ti = 0; ti < 4; ti++) {
        bf16x8 aU = *(const bf16x8*)&sUb[(ti*16 + l15)*80 + k2*32 + lg*8];
        oac[ti] = __builtin_amdgcn_mfma_f32_16x16x32_bf16(aU, bGq[k2], oac[ti], 0, 0, 0);
      }
    #pragma unroll
    for (int ti = 0; ti < 4; ti++)
      #pragma unroll
      for (int r = 0; r < 4; r++)
        b_o[grow + ti*16 + lg*4 + r] = f2b(oac[ti][r]);
    __syncthreads();
    f32x4 sac[4];
    #pragma unroll
    for (int ti = 0; ti < 4; ti++)
      #pragma unroll
      for (int r = 0; r < 4; r++)
        sac[ti][r] = gC * sSf[(ti*16 + lg*4 + r)*68 + tcol];
    #pragma unroll
    for (int k2 = 0; k2 < 2; k2++)
      #pragma unroll
      for (int ti = 0; ti < 4; ti++) {
        bf16x8 aU = *(const bf16x8*)&sUb[(ti*16 + l15)*80 + k2*32 + lg*8];
        sac[ti] = __builtin_amdgcn_mfma_f32_16x16x32_bf16(aU, bKd[k2], sac[ti], 0, 0, 0);
      }
    #pragma unroll
    for (int ti = 0; ti < 4; ti++)
      #pragma unroll
      for (int r = 0; r < 4; r++) {
        int y = ti*16 + lg*4 + r;
        sSf[y*68 + tcol] = sac[ti][r];
        sSb[y*80 + tcol] = f2b(sac[ti][r]);
      }
    __syncthreads();
  }
}

extern "C" void kernel_launch(void* const* d_in, const int* in_sizes, int n_in,
                              void* d_out, int out_size, void* d_ws, size_t ws_size,
                              hipStream_t stream) {
  const float* x   = (const float*)d_in[0];
  const float* n1w = (const float*)d_in[1];
  const float* n2w = (const float*)d_in[2];
  const float* cw  = (const float*)d_in[3];
  const float* cb  = (const float*)d_in[4];
  const float* wq  = (const float*)d_in[5];
  const float* wk  = (const float*)d_in[6];
  const float* wv  = (const float*)d_in[7];
  const float* wb  = (const float*)d_in[8];
  const float* wa  = (const float*)d_in[9];
  const float* wo  = (const float*)d_in[10];
  const float* wg  = (const float*)d_in[11];
  const float* wu  = (const float*)d_in[12];
  const float* wd  = (const float*)d_in[13];
  float* out = (float*)d_out;

  /* weight preprocessing */
  castTqkv_k<<<dim3(50, 16), 256, 0, stream>>>(wq, wk, wv, wb, wa);
  castT_k<<<dim3(16, 16), 256, 0, stream>>>(wo, D_, D_, 5, D_);
  castTgu_k<<<dim3(88, 16), 256, 0, stream>>>(wg, wu);
  castT_k<<<dim3(16, 44), 256, 0, stream>>>(wd, I_, D_, 7, IP_);

  /* norm1 scale + fused norm/conv/silu */
  rmssc_k<<<BT_, 256, 0, stream>>>(x);
  conv2_k<<<ND_ / 256, 256, 0, stream>>>(x, cw, cb, n1w);

  /* fused QKV+gates GEMM (epilogue: l2norm q/k, sigmoid gates) */
  gemm_bf16<<<dim3(25, 32), 256, 0, stream>>>(0, 4, D_, 0, nullptr, nullptr);

  /* chunked WY delta rule */
  prep_k<<<NG_, 256, 0, stream>>>();
  chunkscan_k<<<32, 256, 0, stream>>>();

  /* mix = o@wo + x -> f_h */
  gemm_bf16<<<dim3(8, 32), 256, 0, stream>>>(1, 5, D_, 2, x, nullptr);
  /* hn = rmsnorm(h) -> b_hn */
  rms2_k<<<BT_, 256, 0, stream>>>(n2w);
  /* g,u fused GEMM + swiglu -> b_f */
  gemm_bf16<<<dim3(44, 32), 256, 0, stream>>>(2, 6, D_, 1, nullptr, nullptr);
  /* ffn = f@wd + h -> out */
  gemm_bf16<<<dim3(8, 32), 256, 0, stream>>>(3, 7, IP_, 3, nullptr, out);
}